// Round 4
// baseline (23573.871 us; speedup 1.0000x reference)
//
#include <hip/hip_runtime.h>
#include <hip/hip_bf16.h>

// Model dims
#define BB 64
#define TT 512
#define DD 512
#define EE 6
#define PP 96
#define NHH 4
#define HDD 128
#define FFF 2048

typedef short bf16x8 __attribute__((ext_vector_type(8)));
typedef float f32x4 __attribute__((ext_vector_type(4)));

__device__ __forceinline__ float bf2f(unsigned short u) {
    unsigned int x = ((unsigned int)u) << 16;
    return __uint_as_float(x);
}
__device__ __forceinline__ unsigned short f2bf(float f) {
    __hip_bfloat16 h = __float2bfloat16(f);
    return *reinterpret_cast<unsigned short*>(&h);
}

// ---------------------------------------------------------------------------
// Generic MFMA GEMM:  C[m][n] = alpha * sum_k A[m][k] * W[n][k]  (+bias[n])
// 128x128 tile, BK=32, 256 threads (4 waves, each a 64x64 quadrant of
// 4x4 mfma_f32_16x16x32_bf16). TRANSW stages W[k*ldw+n] (V^T for P·V).
// Batched via blockIdx.z -> (b = z/Hdiv, h = z%Hdiv) offsets.
// ---------------------------------------------------------------------------
template<bool TRANSW, bool BIAS, bool RELU, bool OUTBF16>
__global__ __launch_bounds__(256) void gemm_bt(
    const unsigned short* __restrict__ A, int lda, long long aB, long long aH,
    const unsigned short* __restrict__ W, int ldw, long long wB, long long wH,
    const float* __restrict__ bias,
    void* __restrict__ Cv, int ldc, long long cB, long long cH,
    int K, int Hdiv, float alpha)
{
    __shared__ unsigned short As[128 * 40];
    __shared__ unsigned short Ws[128 * 40];
    int t = threadIdx.x;
    int z = blockIdx.z;
    int zb = z / Hdiv, zh = z - zb * Hdiv;
    long long aOff = (long long)zb * aB + (long long)zh * aH;
    long long wOff = (long long)zb * wB + (long long)zh * wH;
    long long cOff = (long long)zb * cB + (long long)zh * cH;
    int m0 = blockIdx.x * 128, n0 = blockIdx.y * 128;

    int arow = t >> 1, acol = (t & 1) * 16;
    const unsigned short* Ag = A + aOff + (long long)(m0 + arow) * lda + acol;
    const unsigned short* WgN = W + wOff + (long long)(n0 + arow) * ldw + acol;
    int wk = t >> 3, wn = (t & 7) * 16;
    const unsigned short* WgT = W + wOff + n0 + wn;

    int wave = t >> 6, lane = t & 63;
    int wm = (wave & 1) * 64, wn2 = (wave >> 1) * 64;
    int lrow = lane & 15, quad = lane >> 4;

    f32x4 acc[4][4];
    #pragma unroll
    for (int i = 0; i < 4; i++)
        #pragma unroll
        for (int j = 0; j < 4; j++)
            acc[i][j] = (f32x4){0.f, 0.f, 0.f, 0.f};

    for (int k0 = 0; k0 < K; k0 += 32) {
        __syncthreads();
        {
            uint4 a0 = *(const uint4*)(Ag + k0);
            uint4 a1 = *(const uint4*)(Ag + k0 + 8);
            *(uint4*)&As[arow * 40 + acol] = a0;
            *(uint4*)&As[arow * 40 + acol + 8] = a1;
            if (!TRANSW) {
                uint4 w0 = *(const uint4*)(WgN + k0);
                uint4 w1 = *(const uint4*)(WgN + k0 + 8);
                *(uint4*)&Ws[arow * 40 + acol] = w0;
                *(uint4*)&Ws[arow * 40 + acol + 8] = w1;
            } else {
                const unsigned short* p = WgT + (long long)(k0 + wk) * ldw;
                uint4 w0 = *(const uint4*)(p);
                uint4 w1 = *(const uint4*)(p + 8);
                const unsigned short* s0 = (const unsigned short*)&w0;
                const unsigned short* s1 = (const unsigned short*)&w1;
                #pragma unroll
                for (int j = 0; j < 8; j++) Ws[(wn + j) * 40 + wk] = s0[j];
                #pragma unroll
                for (int j = 0; j < 8; j++) Ws[(wn + 8 + j) * 40 + wk] = s1[j];
            }
        }
        __syncthreads();
        bf16x8 af[4], bf[4];
        #pragma unroll
        for (int i = 0; i < 4; i++)
            af[i] = *(const bf16x8*)&As[(wm + i * 16 + lrow) * 40 + quad * 8];
        #pragma unroll
        for (int j = 0; j < 4; j++)
            bf[j] = *(const bf16x8*)&Ws[(wn2 + j * 16 + lrow) * 40 + quad * 8];
        #pragma unroll
        for (int i = 0; i < 4; i++)
            #pragma unroll
            for (int j = 0; j < 4; j++)
                acc[i][j] = __builtin_amdgcn_mfma_f32_16x16x32_bf16(af[i], bf[j], acc[i][j], 0, 0, 0);
    }

    #pragma unroll
    for (int i = 0; i < 4; i++) {
        #pragma unroll
        for (int j = 0; j < 4; j++) {
            #pragma unroll
            for (int r = 0; r < 4; r++) {
                int row = m0 + wm + i * 16 + quad * 4 + r;
                int col = n0 + wn2 + j * 16 + lrow;
                float v = acc[i][j][r] * alpha;
                if (BIAS) v += bias[col];
                if (RELU) v = fmaxf(v, 0.f);
                long long idx = cOff + (long long)row * ldc + col;
                if (OUTBF16) ((unsigned short*)Cv)[idx] = f2bf(v);
                else         ((float*)Cv)[idx] = v;
            }
        }
    }
}

// ---------------------------------------------------------------------------
__global__ void cvt_k(const float* __restrict__ in, unsigned short* __restrict__ out, int n)
{
    int i = blockIdx.x * 256 + threadIdx.x;
    int stride = gridDim.x * 256;
    for (; i < n; i += stride) out[i] = f2bf(in[i]);
}

// ---------------------------------------------------------------------------
// GARCH: per-batch variance + 511-step scalar recurrence. 1 block, lane = batch.
// ---------------------------------------------------------------------------
__global__ __launch_bounds__(64) void garch_k(
    const float* __restrict__ xe, const float* __restrict__ omega,
    const float* __restrict__ alpha, const float* __restrict__ beta,
    float* __restrict__ vol)
{
    int b = threadIdx.x;
    float sm = 0.f, sq = 0.f;
    for (int t2 = 0; t2 < TT; t2++) {
        float r = xe[((long long)b * TT + t2) * EE + 5];
        sm += r; sq += r * r;
    }
    float mean = sm / 512.f;
    float var = (sq - 512.f * mean * mean) / 511.f;
    float h = var + 1e-6f;
    float om = log1pf(expf(omega[0]));
    float al = 0.2f / (1.f + expf(-alpha[0]));
    float be = 0.8f / (1.f + expf(-beta[0]));
    for (int t2 = 0; t2 < TT - 1; t2++) {
        float r = xe[((long long)b * TT + t2) * EE + 5];
        h = om + al * r * r + be * h;
    }
    vol[b] = sqrtf(h);
}

// ---------------------------------------------------------------------------
// Persistent LSTM v4 — 64-block geometry, chunk-overlapped staging.
//
// Round-2 post-mortem: v3 was BW-bound on the agent-scope load path
// (~2.4 TB/s): 256 blocks x 128 KB h-broadcast = 32 MB/step = 13.3 us/step.
// Coherent bytes scale with Nblocks; compute/CU with 1/Nblocks. Balance at
// N=64: stage 8 MB/step (3.3 us) ~= compute 1.05 MFMA/CU (3.4 us).
//
// Geometry: 64 blocks x 1024 threads (16 waves). wave = dl*2+kh:
//   dl = wave>>1 (0..7): block's dim d = blk*8+dl;  kh = wave&1: k-parity.
// h staged in 8 chunks of 64 k (16 KB each); chunk parity kh computes
// chunk c-1 (64 k x 4 gates = 256 FMA) while chunk c's coherent loads fly.
// Weights read as wave-uniform float4 broadcasts (1 L1 req/instr,
// 4096 req/CU/step) from L1/L2-resident 64 KB/block slice.
// Barrier: flat 64-way counter per step (relaxed AGENT atomics, vmcnt(0)
// before arrival — proven primitives from rounds 1-2).
// Deadlock-safe by capacity: 64 blocks, 1/CU (144 KB LDS), grid << CUs.
// ---------------------------------------------------------------------------
__global__ __launch_bounds__(1024, 1) void lstm_persist4_k(
    const float* __restrict__ xe, const float* __restrict__ w_hh,
    const float* __restrict__ w_ih, const float* __restrict__ b_ih,
    const float* __restrict__ b_hh,
    float* __restrict__ h0, float* __restrict__ h1,
    float* __restrict__ xT,
    unsigned* __restrict__ root)
{
    __shared__ float hs[512 * 64];      // h[k][b], 128 KB
    __shared__ float part[16][4][64];   // per-wave gate partials, 16 KB

    int blk = blockIdx.x;               // 0..63
    int tid = threadIdx.x;              // 0..1023
    int wave = tid >> 6, lane = tid & 63;
    int dl = wave >> 1;                 // 0..7
    int kh = wave & 1;                  // 0..1
    int d = blk * 8 + dl;               // 0..511

    const float* w0r = w_hh + (long long)(0    + d) * 512;
    const float* w1r = w_hh + (long long)(512  + d) * 512;
    const float* w2r = w_hh + (long long)(1024 + d) * 512;
    const float* w3r = w_hh + (long long)(1536 + d) * 512;

    bool fin = (kh == 0);
    float wi[4][6], bs[4];
    if (fin) {
        #pragma unroll
        for (int g = 0; g < 4; g++) {
            int row = g * 512 + d;
            #pragma unroll
            for (int e = 0; e < 6; e++) wi[g][e] = w_ih[row * 6 + e];
            bs[g] = b_ih[row] + b_hh[row];
        }
    }
    float c = 0.f;

    for (int t = 0; t < TT; t++) {
        const float* hin  = (t & 1) ? h1 : h0;
        float*       hout = (t & 1) ? h0 : h1;

        // xe(t) prefetch for finalize waves (cached loads, hide under stage)
        float x0 = 0.f, x1 = 0.f, x2 = 0.f, x3 = 0.f, x4 = 0.f, x5 = 0.f;
        if (fin) {
            const float* xr = xe + ((long long)lane * TT + t) * EE;
            x0 = xr[0]; x1 = xr[1]; x2 = xr[2];
            x3 = xr[3]; x4 = xr[4]; x5 = xr[5];
        }

        float a0 = 0.f, a1 = 0.f, a2 = 0.f, a3 = 0.f;

        // ---- chunk 0 stage (4 coherent dwords/thread = 16 KB/block) ----
        {
            float hv[4];
            #pragma unroll
            for (int j = 0; j < 4; j++)
                hv[j] = __hip_atomic_load(&hin[j * 1024 + tid], __ATOMIC_RELAXED,
                                          __HIP_MEMORY_SCOPE_AGENT);
            #pragma unroll
            for (int j = 0; j < 4; j++) hs[j * 1024 + tid] = hv[j];
        }
        __syncthreads();

        // ---- chunks 1..7: stage chunk c while computing chunk c-1 ----
        #pragma unroll
        for (int c8 = 1; c8 < 8; c8++) {
            float hw[4];
            #pragma unroll
            for (int j = 0; j < 4; j++)
                hw[j] = __hip_atomic_load(&hin[c8 * 4096 + j * 1024 + tid],
                                          __ATOMIC_RELAXED,
                                          __HIP_MEMORY_SCOPE_AGENT);
            if (((c8 - 1) & 1) == kh) {     // wave-uniform: my chunk parity
                int kb = (c8 - 1) * 64;
                #pragma unroll 4
                for (int kk = 0; kk < 64; kk += 4) {
                    int k = kb + kk;
                    float4 w40 = *(const float4*)(w0r + k);
                    float4 w41 = *(const float4*)(w1r + k);
                    float4 w42 = *(const float4*)(w2r + k);
                    float4 w43 = *(const float4*)(w3r + k);
                    float h0v = hs[(k + 0) * 64 + lane];
                    float h1v = hs[(k + 1) * 64 + lane];
                    float h2v = hs[(k + 2) * 64 + lane];
                    float h3v = hs[(k + 3) * 64 + lane];
                    a0 += h0v * w40.x + h1v * w40.y + h2v * w40.z + h3v * w40.w;
                    a1 += h0v * w41.x + h1v * w41.y + h2v * w41.z + h3v * w41.w;
                    a2 += h0v * w42.x + h1v * w42.y + h2v * w42.z + h3v * w42.w;
                    a3 += h0v * w43.x + h1v * w43.y + h2v * w43.z + h3v * w43.w;
                }
            }
            #pragma unroll
            for (int j = 0; j < 4; j++)
                hs[c8 * 4096 + j * 1024 + tid] = hw[j];
            __syncthreads();
        }
        // ---- last chunk (7) belongs to kh==1 ----
        if (kh == 1) {
            int kb = 7 * 64;
            #pragma unroll 4
            for (int kk = 0; kk < 64; kk += 4) {
                int k = kb + kk;
                float4 w40 = *(const float4*)(w0r + k);
                float4 w41 = *(const float4*)(w1r + k);
                float4 w42 = *(const float4*)(w2r + k);
                float4 w43 = *(const float4*)(w3r + k);
                float h0v = hs[(k + 0) * 64 + lane];
                float h1v = hs[(k + 1) * 64 + lane];
                float h2v = hs[(k + 2) * 64 + lane];
                float h3v = hs[(k + 3) * 64 + lane];
                a0 += h0v * w40.x + h1v * w40.y + h2v * w40.z + h3v * w40.w;
                a1 += h0v * w41.x + h1v * w41.y + h2v * w41.z + h3v * w41.w;
                a2 += h0v * w42.x + h1v * w42.y + h2v * w42.z + h3v * w42.w;
                a3 += h0v * w43.x + h1v * w43.y + h2v * w43.z + h3v * w43.w;
            }
        }

        part[wave][0][lane] = a0; part[wave][1][lane] = a1;
        part[wave][2][lane] = a2; part[wave][3][lane] = a3;
        __syncthreads();   // sync1: partials visible

        if (fin) {
            int pw = wave + 1;   // kh==1 partner, same dl
            float s0 = a0 + part[pw][0][lane];
            float s1 = a1 + part[pw][1][lane];
            float s2 = a2 + part[pw][2][lane];
            float s3 = a3 + part[pw][3][lane];
            float pi = s0 + x0*wi[0][0] + x1*wi[0][1] + x2*wi[0][2]
                          + x3*wi[0][3] + x4*wi[0][4] + x5*wi[0][5] + bs[0];
            float pf = s1 + x0*wi[1][0] + x1*wi[1][1] + x2*wi[1][2]
                          + x3*wi[1][3] + x4*wi[1][4] + x5*wi[1][5] + bs[1];
            float pg = s2 + x0*wi[2][0] + x1*wi[2][1] + x2*wi[2][2]
                          + x3*wi[2][3] + x4*wi[2][4] + x5*wi[2][5] + bs[2];
            float po = s3 + x0*wi[3][0] + x1*wi[3][1] + x2*wi[3][2]
                          + x3*wi[3][3] + x4*wi[3][4] + x5*wi[3][5] + bs[3];
            float ig = 1.f / (1.f + __expf(-pi));
            float fg = 1.f / (1.f + __expf(-pf));
            float gg = tanhf(pg);
            float og = 1.f / (1.f + __expf(-po));
            c = fg * c + ig * gg;
            float hn = og * tanhf(c);
            __hip_atomic_store(&hout[d * 64 + lane], hn, __ATOMIC_RELAXED,
                               __HIP_MEMORY_SCOPE_AGENT);
            xT[((long long)t * 512 + d) * 64 + lane] = hn;
            // h stores must be at the coherence point before arrival.
            asm volatile("s_waitcnt vmcnt(0)" ::: "memory");
        }
        __syncthreads();   // sync2: all fin waves' stores landed

        if (t < TT - 1) {
            if (tid == 0) {
                __hip_atomic_fetch_add(&root[t], 1u,
                    __ATOMIC_RELAXED, __HIP_MEMORY_SCOPE_AGENT);
                unsigned tries = 0;
                while (__hip_atomic_load(&root[t], __ATOMIC_RELAXED,
                                         __HIP_MEMORY_SCOPE_AGENT) < 64u) {
                    __builtin_amdgcn_s_sleep(2);
                    if (++tries > 100000000u) break;   // fail loudly, never wedge
                }
            }
            __syncthreads();   // sync3: release whole block into step t+1
        }
    }
}

// ---------------------------------------------------------------------------
// Transpose xT[t][d][b] -> XB[b][t][d] bf16
// ---------------------------------------------------------------------------
__global__ __launch_bounds__(256) void transpose_k(
    const float* __restrict__ xT, unsigned short* __restrict__ XB_)
{
    __shared__ float tile[64][65];
    int dc = blockIdx.x, t = blockIdx.y;
    int tid = threadIdx.x;
    int bcol = tid & 63, grp = tid >> 6;
    #pragma unroll
    for (int j = 0; j < 16; j++) {
        int i = grp * 16 + j;
        tile[i][bcol] = xT[((long long)t * 512 + dc * 64 + i) * 64 + bcol];
    }
    __syncthreads();
    #pragma unroll
    for (int j = 0; j < 16; j++) {
        int brow = grp * 16 + j;
        float v = tile[bcol][brow];
        long long idx = ((long long)brow * TT + t) * DD + dc * 64 + bcol;
        XB_[idx] = f2bf(v);
    }
}

// ---------------------------------------------------------------------------
// Softmax over last dim (512), in-place on bf16 scores. One wave per row.
// ---------------------------------------------------------------------------
__global__ __launch_bounds__(256) void softmax_k(unsigned short* __restrict__ S)
{
    long long row = (long long)blockIdx.x * 4 + (threadIdx.x >> 6);
    int lane = threadIdx.x & 63;
    unsigned short* p = S + row * 512 + lane * 8;
    uint4 raw = *(const uint4*)p;
    unsigned short* u = (unsigned short*)&raw;
    float v[8];
    float m = -1e30f;
    #pragma unroll
    for (int j = 0; j < 8; j++) { v[j] = bf2f(u[j]); m = fmaxf(m, v[j]); }
    #pragma unroll
    for (int off = 1; off < 64; off <<= 1) m = fmaxf(m, __shfl_xor(m, off));
    float s = 0.f;
    #pragma unroll
    for (int j = 0; j < 8; j++) { v[j] = __expf(v[j] - m); s += v[j]; }
    #pragma unroll
    for (int off = 1; off < 64; off <<= 1) s += __shfl_xor(s, off);
    float inv = 1.f / s;
    unsigned int pk[4];
    #pragma unroll
    for (int j = 0; j < 4; j++)
        pk[j] = (unsigned int)f2bf(v[2 * j] * inv) | ((unsigned int)f2bf(v[2 * j + 1] * inv) << 16);
    *(uint4*)p = make_uint4(pk[0], pk[1], pk[2], pk[3]);
}

// ---------------------------------------------------------------------------
// Residual + LayerNorm: XB = LN(XB + Y)*g + b  (bf16 residual stream).
// ---------------------------------------------------------------------------
__global__ __launch_bounds__(256) void ln_k(
    unsigned short* XB_, const float* __restrict__ Y_,
    const float* __restrict__ g, const float* __restrict__ b2)
{
    long long row = (long long)blockIdx.x * 4 + (threadIdx.x >> 6);
    int lane = threadIdx.x & 63;
    long long base = row * 512 + lane * 8;
    float s[8];
    {
        uint4 xr = *(const uint4*)&XB_[base];
        const unsigned short* xu = (const unsigned short*)&xr;
        float4 y0 = *(const float4*)&Y_[base];
        float4 y1 = *(const float4*)&Y_[base + 4];
        s[0] = bf2f(xu[0]) + y0.x; s[1] = bf2f(xu[1]) + y0.y;
        s[2] = bf2f(xu[2]) + y0.z; s[3] = bf2f(xu[3]) + y0.w;
        s[4] = bf2f(xu[4]) + y1.x; s[5] = bf2f(xu[5]) + y1.y;
        s[6] = bf2f(xu[6]) + y1.z; s[7] = bf2f(xu[7]) + y1.w;
    }
    float sm = 0.f, sq = 0.f;
    #pragma unroll
    for (int j = 0; j < 8; j++) { sm += s[j]; sq += s[j] * s[j]; }
    #pragma unroll
    for (int off = 1; off < 64; off <<= 1) {
        sm += __shfl_xor(sm, off);
        sq += __shfl_xor(sq, off);
    }
    float mean = sm * (1.f / 512.f);
    float var = sq * (1.f / 512.f) - mean * mean;
    float rstd = rsqrtf(var + 1e-5f);
    int col = lane * 8;
    float o[8];
    #pragma unroll
    for (int j = 0; j < 8; j++) o[j] = (s[j] - mean) * rstd * g[col + j] + b2[col + j];
    unsigned int pk[4];
    #pragma unroll
    for (int j = 0; j < 4; j++)
        pk[j] = (unsigned int)f2bf(o[2 * j]) | ((unsigned int)f2bf(o[2 * j + 1]) << 16);
    *(uint4*)&XB_[base] = make_uint4(pk[0], pk[1], pk[2], pk[3]);
}

// ---------------------------------------------------------------------------
// Heads: garch_base + gate * ai_residual. One block per batch.
// ---------------------------------------------------------------------------
__global__ __launch_bounds__(128) void head_k(
    const unsigned short* __restrict__ XB_, const float* __restrict__ xe,
    const float* __restrict__ vol,
    const float* __restrict__ rh_w, const float* __restrict__ rh_b,
    const float* __restrict__ g1_w, const float* __restrict__ g1_b,
    const float* __restrict__ g2_w, const float* __restrict__ g2_b,
    const float* __restrict__ gp_w, const float* __restrict__ gp_b,
    float* __restrict__ out)
{
    int b = blockIdx.x, t = threadIdx.x;
    __shared__ float xl[512];
    __shared__ float hid[256];
    for (int j = t; j < 512; j += 128)
        xl[j] = bf2f(XB_[((long long)b * TT + (TT - 1)) * DD + j]);
    float gin[7];
    #pragma unroll
    for (int e = 0; e < 6; e++) gin[e] = xe[((long long)b * TT + (TT - 1)) * EE + e];
    gin[6] = vol[b];
    for (int j = t; j < 256; j += 128) {
        float s = g1_b[j];
        #pragma unroll
        for (int e = 0; e < 7; e++) s += g1_w[j * 7 + e] * gin[e];
        hid[j] = fmaxf(s, 0.f);
    }
    __syncthreads();
    for (int p = t; p < 96; p += 128) {
        float ai = rh_b[p];
        for (int j = 0; j < 512; j++) ai += xl[j] * rh_w[p * 512 + j];
        float gs = g2_b[p];
        for (int j = 0; j < 256; j++) gs += hid[j] * g2_w[p * 256 + j];
        float gate = 1.f / (1.f + expf(-gs));
        out[b * PP + p] = vol[b] * gp_w[p] + gp_b[p] + gate * ai;
    }
}

// ---------------------------------------------------------------------------
// Launch.  Workspace layout (bytes, total ~147.2 MB):
//   XB   bf16 residual  @ 0           (33554432)
//   Y    fp32 branch    @ 33554432    (67108864)   [aliases LSTM xT]
//   CH   chunk region   @ 100663296   (33554432)
//        QKVc @ +0 | SCc @ +12582912 | CTXc @ +29360128 ; HIDc @ +0 [FFN]
//   WB   bf16 weights   @ 134217728   (12582912)
//   HT0/HT1             @ 146800640   (2 x 131072)
//   BAR  barrier slots  @ 147062784   (root 512 u32)
//   VOL                 @ 147193856   (256)
// ---------------------------------------------------------------------------
extern "C" void kernel_launch(void* const* d_in, const int* in_sizes, int n_in,
                              void* d_out, int out_size, void* d_ws, size_t ws_size,
                              hipStream_t stream)
{
    const float* x_enc      = (const float*)d_in[0];
    const float* omega      = (const float*)d_in[4];
    const float* alpha      = (const float*)d_in[5];
    const float* beta       = (const float*)d_in[6];
    const float* gp_w       = (const float*)d_in[7];
    const float* gp_b       = (const float*)d_in[8];
    const float* w_ih       = (const float*)d_in[9];
    const float* w_hh       = (const float*)d_in[10];
    const float* b_ih       = (const float*)d_in[11];
    const float* b_hh       = (const float*)d_in[12];
    const float* attn_in_w  = (const float*)d_in[13];
    const float* attn_in_b  = (const float*)d_in[14];
    const float* attn_out_w = (const float*)d_in[15];
    const float* attn_out_b = (const float*)d_in[16];
    const float* ln1_g      = (const float*)d_in[17];
    const float* ln1_b      = (const float*)d_in[18];
    const float* ffn_w1     = (const float*)d_in[19];
    const float* ffn_b1     = (const float*)d_in[20];
    const float* ffn_w2     = (const float*)d_in[21];
    const float* ffn_b2     = (const float*)d_in[22];
    const float* ln2_g      = (const float*)d_in[23];
    const float* ln2_b      = (const float*)d_in[24];
    const float* rh_w       = (const float*)d_in[25];
    const float* rh_b       = (const float*)d_in[26];
    const float* g1_w       = (const float*)d_in[27];
    const float* g1_b       = (const float*)d_in[28];
    const float* g2_w       = (const float*)d_in[29];
    const float* g2_b       = (const float*)d_in[30];

    char* ws = (char*)d_ws;
    unsigned short* XB   = (unsigned short*)(ws + 0);
    float*          Y    = (float*)(ws + 33554432LL);
    float*          XT   = Y;
    unsigned short* QKVc = (unsigned short*)(ws + 100663296LL);
    unsigned short* SCc  = (unsigned short*)(ws + 113246208LL);
    unsigned short* CTXc = (unsigned short*)(ws + 130023424LL);
    unsigned short* HIDc = (unsigned short*)(ws + 100663296LL);
    unsigned short* WATI = (unsigned short*)(ws + 134217728LL);
    unsigned short* WATO = WATI + 1572864;
    unsigned short* WF1  = WATI + 2097152;
    unsigned short* WF2  = WATI + 4194304;
    float*          HT0  = (float*)(ws + 146800640LL);
    float*          HT1  = (float*)(ws + 146931712LL);
    unsigned*       ROOT = (unsigned*)(ws + 147062784LL);
    float*          VOL  = (float*)(ws + 147193856LL);

    hipMemsetAsync(HT0, 0, 131072, stream);
    hipMemsetAsync(ROOT, 0, 2048, stream);

    cvt_k<<<2048, 256, 0, stream>>>(attn_in_w,  WATI, 1572864);
    cvt_k<<<1024, 256, 0, stream>>>(attn_out_w, WATO, 524288);
    cvt_k<<<2048, 256, 0, stream>>>(ffn_w1,     WF1,  2097152);
    cvt_k<<<2048, 256, 0, stream>>>(ffn_w2,     WF2,  2097152);

    garch_k<<<1, 64, 0, stream>>>(x_enc, omega, alpha, beta, VOL);

    // Persistent LSTM v4: 64 blocks x 1024 threads, chunk-overlapped staging.
    lstm_persist4_k<<<64, 1024, 0, stream>>>(x_enc, w_hh, w_ih, b_ih, b_hh,
                                             HT0, HT1, XT, ROOT);

    transpose_k<<<dim3(8, 512, 1), 256, 0, stream>>>(XT, XB);

    for (int l = 0; l < 2; l++) {
        // Attention, chunked over batches: 8 chunks x 8 batches (4096 rows)
        for (int c = 0; c < 8; c++) {
            long long rowOff = (long long)c * 8 * 512;
            gemm_bt<false, true, false, true><<<dim3(32, 12, 1), 256, 0, stream>>>(
                XB + rowOff * 512, 512, 0, 0,
                WATI + l * 786432, 512, 0, 0, attn_in_b + l * 1536,
                QKVc, 1536, 0, 0, 512, 1, 1.0f);
            gemm_bt<false, false, false, true><<<dim3(4, 4, 32), 256, 0, stream>>>(
                QKVc, 1536, 786432LL, 128LL, QKVc + 512, 1536, 786432LL, 128LL, nullptr,
                SCc, 512, 1048576LL, 262144LL, 128, 4, 0.088388347648318447f);
            softmax_k<<<4096, 256, 0, stream>>>(SCc);
            gemm_bt<true, false, false, true><<<dim3(4, 1, 32), 256, 0, stream>>>(
                SCc, 512, 1048576LL, 262144LL, QKVc + 1024, 1536, 786432LL, 128LL, nullptr,
                CTXc, 512, 262144LL, 128LL, 512, 4, 1.0f);
            gemm_bt<false, true, false, false><<<dim3(32, 4, 1), 256, 0, stream>>>(
                CTXc, 512, 0, 0, WATO + l * 262144, 512, 0, 0, attn_out_b + l * 512,
                Y + rowOff * 512, 512, 0, 0, 512, 1, 1.0f);
        }
        ln_k<<<8192, 256, 0, stream>>>(XB, Y, ln1_g + l * 512, ln1_b + l * 512);

        // FFN, chunked over rows: 4 chunks x 8192 rows
        for (int mc = 0; mc < 4; mc++) {
            long long rowOff = (long long)mc * 8192;
            gemm_bt<false, true, true, true><<<dim3(64, 16, 1), 256, 0, stream>>>(
                XB + rowOff * 512, 512, 0, 0,
                WF1 + l * 1048576, 512, 0, 0, ffn_b1 + l * 2048,
                HIDc, 2048, 0, 0, 512, 1, 1.0f);
            gemm_bt<false, true, false, false><<<dim3(64, 4, 1), 256, 0, stream>>>(
                HIDc, 2048, 0, 0, WF2 + l * 1048576, 2048, 0, 0, ffn_b2 + l * 512,
                Y + rowOff * 512, 512, 0, 0, 2048, 1, 1.0f);
        }
        ln_k<<<8192, 256, 0, stream>>>(XB, Y, ln2_g + l * 512, ln2_b + l * 512);
    }

    head_k<<<64, 128, 0, stream>>>(XB, x_enc, VOL, rh_w, rh_b,
                                   g1_w, g1_b, g2_w, g2_b, gp_w, gp_b,
                                   (float*)d_out);
}

// Round 5
// 15082.932 us; speedup vs baseline: 1.5630x; 1.5630x over previous
//
#include <hip/hip_runtime.h>
#include <hip/hip_bf16.h>

// Model dims
#define BB 64
#define TT 512
#define DD 512
#define EE 6
#define PP 96
#define NHH 4
#define HDD 128
#define FFF 2048

typedef short bf16x8 __attribute__((ext_vector_type(8)));
typedef float f32x4 __attribute__((ext_vector_type(4)));

__device__ __forceinline__ float bf2f(unsigned short u) {
    unsigned int x = ((unsigned int)u) << 16;
    return __uint_as_float(x);
}
__device__ __forceinline__ unsigned short f2bf(float f) {
    __hip_bfloat16 h = __float2bfloat16(f);
    return *reinterpret_cast<unsigned short*>(&h);
}

// ---------------------------------------------------------------------------
// Generic MFMA GEMM:  C[m][n] = alpha * sum_k A[m][k] * W[n][k]  (+bias[n])
// 128x128 tile, BK=32, 256 threads (4 waves, each a 64x64 quadrant of
// 4x4 mfma_f32_16x16x32_bf16). TRANSW stages W[k*ldw+n] (V^T for P·V).
// Batched via blockIdx.z -> (b = z/Hdiv, h = z%Hdiv) offsets.
// ---------------------------------------------------------------------------
template<bool TRANSW, bool BIAS, bool RELU, bool OUTBF16>
__global__ __launch_bounds__(256) void gemm_bt(
    const unsigned short* __restrict__ A, int lda, long long aB, long long aH,
    const unsigned short* __restrict__ W, int ldw, long long wB, long long wH,
    const float* __restrict__ bias,
    void* __restrict__ Cv, int ldc, long long cB, long long cH,
    int K, int Hdiv, float alpha)
{
    __shared__ unsigned short As[128 * 40];
    __shared__ unsigned short Ws[128 * 40];
    int t = threadIdx.x;
    int z = blockIdx.z;
    int zb = z / Hdiv, zh = z - zb * Hdiv;
    long long aOff = (long long)zb * aB + (long long)zh * aH;
    long long wOff = (long long)zb * wB + (long long)zh * wH;
    long long cOff = (long long)zb * cB + (long long)zh * cH;
    int m0 = blockIdx.x * 128, n0 = blockIdx.y * 128;

    int arow = t >> 1, acol = (t & 1) * 16;
    const unsigned short* Ag = A + aOff + (long long)(m0 + arow) * lda + acol;
    const unsigned short* WgN = W + wOff + (long long)(n0 + arow) * ldw + acol;
    int wk = t >> 3, wn = (t & 7) * 16;
    const unsigned short* WgT = W + wOff + n0 + wn;

    int wave = t >> 6, lane = t & 63;
    int wm = (wave & 1) * 64, wn2 = (wave >> 1) * 64;
    int lrow = lane & 15, quad = lane >> 4;

    f32x4 acc[4][4];
    #pragma unroll
    for (int i = 0; i < 4; i++)
        #pragma unroll
        for (int j = 0; j < 4; j++)
            acc[i][j] = (f32x4){0.f, 0.f, 0.f, 0.f};

    for (int k0 = 0; k0 < K; k0 += 32) {
        __syncthreads();
        {
            uint4 a0 = *(const uint4*)(Ag + k0);
            uint4 a1 = *(const uint4*)(Ag + k0 + 8);
            *(uint4*)&As[arow * 40 + acol] = a0;
            *(uint4*)&As[arow * 40 + acol + 8] = a1;
            if (!TRANSW) {
                uint4 w0 = *(const uint4*)(WgN + k0);
                uint4 w1 = *(const uint4*)(WgN + k0 + 8);
                *(uint4*)&Ws[arow * 40 + acol] = w0;
                *(uint4*)&Ws[arow * 40 + acol + 8] = w1;
            } else {
                const unsigned short* p = WgT + (long long)(k0 + wk) * ldw;
                uint4 w0 = *(const uint4*)(p);
                uint4 w1 = *(const uint4*)(p + 8);
                const unsigned short* s0 = (const unsigned short*)&w0;
                const unsigned short* s1 = (const unsigned short*)&w1;
                #pragma unroll
                for (int j = 0; j < 8; j++) Ws[(wn + j) * 40 + wk] = s0[j];
                #pragma unroll
                for (int j = 0; j < 8; j++) Ws[(wn + 8 + j) * 40 + wk] = s1[j];
            }
        }
        __syncthreads();
        bf16x8 af[4], bf[4];
        #pragma unroll
        for (int i = 0; i < 4; i++)
            af[i] = *(const bf16x8*)&As[(wm + i * 16 + lrow) * 40 + quad * 8];
        #pragma unroll
        for (int j = 0; j < 4; j++)
            bf[j] = *(const bf16x8*)&Ws[(wn2 + j * 16 + lrow) * 40 + quad * 8];
        #pragma unroll
        for (int i = 0; i < 4; i++)
            #pragma unroll
            for (int j = 0; j < 4; j++)
                acc[i][j] = __builtin_amdgcn_mfma_f32_16x16x32_bf16(af[i], bf[j], acc[i][j], 0, 0, 0);
    }

    #pragma unroll
    for (int i = 0; i < 4; i++) {
        #pragma unroll
        for (int j = 0; j < 4; j++) {
            #pragma unroll
            for (int r = 0; r < 4; r++) {
                int row = m0 + wm + i * 16 + quad * 4 + r;
                int col = n0 + wn2 + j * 16 + lrow;
                float v = acc[i][j][r] * alpha;
                if (BIAS) v += bias[col];
                if (RELU) v = fmaxf(v, 0.f);
                long long idx = cOff + (long long)row * ldc + col;
                if (OUTBF16) ((unsigned short*)Cv)[idx] = f2bf(v);
                else         ((float*)Cv)[idx] = v;
            }
        }
    }
}

// ---------------------------------------------------------------------------
__global__ void cvt_k(const float* __restrict__ in, unsigned short* __restrict__ out, int n)
{
    int i = blockIdx.x * 256 + threadIdx.x;
    int stride = gridDim.x * 256;
    for (; i < n; i += stride) out[i] = f2bf(in[i]);
}

// ---------------------------------------------------------------------------
// GARCH: per-batch variance + 511-step scalar recurrence. 1 block, lane = batch.
// ---------------------------------------------------------------------------
__global__ __launch_bounds__(64) void garch_k(
    const float* __restrict__ xe, const float* __restrict__ omega,
    const float* __restrict__ alpha, const float* __restrict__ beta,
    float* __restrict__ vol)
{
    int b = threadIdx.x;
    float sm = 0.f, sq = 0.f;
    for (int t2 = 0; t2 < TT; t2++) {
        float r = xe[((long long)b * TT + t2) * EE + 5];
        sm += r; sq += r * r;
    }
    float mean = sm / 512.f;
    float var = (sq - 512.f * mean * mean) / 511.f;
    float h = var + 1e-6f;
    float om = log1pf(expf(omega[0]));
    float al = 0.2f / (1.f + expf(-alpha[0]));
    float be = 0.8f / (1.f + expf(-beta[0]));
    for (int t2 = 0; t2 < TT - 1; t2++) {
        float r = xe[((long long)b * TT + t2) * EE + 5];
        h = om + al * r * r + be * h;
    }
    vol[b] = sqrtf(h);
}

// ---------------------------------------------------------------------------
// Persistent LSTM v5 — batch-partitioned, weights-in-registers.
//
// Round-3 post-mortem: v4 (64 blocks, chunked staging) was latency-bound:
// the coherent MALL path's achieved BW scales with outstanding requests;
// 8 chunk-barriers/step each exposed a full round trip -> 41.6 us/step.
// v3 (256 blocks, one staging burst of 16 loads/thread) sustained 2.4 TB/s.
//
// v5 keeps v3's staging SHAPE (2048 waves, 16 coherent loads back-to-back,
// one sync) but kills 8x of the traffic using batch independence:
//   grid 256 = 32 dim-groups (16 dims) x 8 batch-groups (8 batches).
//   Block stages only ITS 8 batches' h: 16 KB -> 4 MB/step fleet-wide.
// w_hh is held in REGISTERS: thread (i = dim-in-group, ks = k-slice) owns
// w[4 gates][32 k] = 128 VGPR (statically indexed, fully unrolled).
// Outer-product: per k, 8 LDS reads (h[b]) -> 32 FMA (4g x 8b accs): 4:1
// FMA:LDS ratio (v3 was 1:1). Reduce over 16 k-slices = in-wave butterfly
// (shfl_xor 1/2/4/8 within 16-lane groups). Lanes ks<8 finalize one
// (dim, b) cell each; c-state in a register.
// Barrier: per batch-column (8 independent 32-block barriers), per-step
// slot root[t*8+col]; relaxed AGENT atomics + vmcnt(0) before arrival
// (proven primitives). Deadlock-safe by capacity: ~230 VGPR, 17 KB LDS ->
// >=2 blocks/CU capacity, grid 256 <= 512.
// hbuf layout: h[b64][d512] (row = batch), contiguous 16 KB per column.
// ---------------------------------------------------------------------------
__global__ __launch_bounds__(256, 2) void lstm_wreg_k(
    const float* __restrict__ xe, const float* __restrict__ w_hh,
    const float* __restrict__ w_ih, const float* __restrict__ b_ih,
    const float* __restrict__ b_hh,
    float* __restrict__ h0, float* __restrict__ h1,
    float* __restrict__ xT,
    unsigned* __restrict__ root)
{
    __shared__ float hs[8][528];   // h[b][k + k/32] pad: bank-conflict-free
    __shared__ float xs[8][8];     // x_t[b][e]

    int blk = blockIdx.x;          // 0..255
    int dgG = blk >> 3;            // 0..31 dim group
    int bG  = blk & 7;             // 0..7  batch group
    int tid = threadIdx.x;         // 0..255
    int i   = tid >> 4;            // 0..15 dim within group
    int ks  = tid & 15;            // 0..15 k-slice (32 k each)
    int D   = dgG * 16 + i;        // global dim 0..511

    // ---- permanent register-resident w_hh slice: w[gate][32] ----
    float w[4][32];
    #pragma unroll
    for (int g = 0; g < 4; g++) {
        const float* wr = w_hh + ((long long)(g * 512 + D)) * 512 + ks * 32;
        #pragma unroll
        for (int jj = 0; jj < 8; jj++) {
            float4 v = *(const float4*)(wr + jj * 4);
            w[g][jj * 4 + 0] = v.x; w[g][jj * 4 + 1] = v.y;
            w[g][jj * 4 + 2] = v.z; w[g][jj * 4 + 3] = v.w;
        }
    }
    float wi[4][6], bs[4];
    #pragma unroll
    for (int g = 0; g < 4; g++) {
        int row = g * 512 + D;
        #pragma unroll
        for (int e = 0; e < 6; e++) wi[g][e] = w_ih[row * 6 + e];
        bs[g] = b_ih[row] + b_hh[row];
    }
    float c = 0.f;   // cell state for (D, b=ks) on lanes ks<8

    for (int t = 0; t < TT; t++) {
        const float* hin  = (t & 1) ? h1 : h0;
        float*       hout = (t & 1) ? h0 : h1;

        // ---- stage h[8][512] (16 KB) via one burst of coherent loads ----
        float hv[16];
        #pragma unroll
        for (int jj = 0; jj < 16; jj++) {
            int flat = jj * 256 + tid;            // 0..4095
            int row = flat >> 9, k = flat & 511;
            hv[jj] = __hip_atomic_load(&hin[(bG * 8 + row) * 512 + k],
                                       __ATOMIC_RELAXED,
                                       __HIP_MEMORY_SCOPE_AGENT);
        }
        if (tid < 64 && (tid & 7) < 6) {
            int b = tid >> 3, e = tid & 7;
            xs[b][e] = xe[((long long)(bG * 8 + b) * TT + t) * EE + e];
        }
        #pragma unroll
        for (int jj = 0; jj < 16; jj++) {
            int flat = jj * 256 + tid;
            int row = flat >> 9, k = flat & 511;
            hs[row][k + (k >> 5)] = hv[jj];
        }
        __syncthreads();

        // ---- outer-product dot: acc[gate][batch] over this k-slice ----
        float acc[4][8];
        #pragma unroll
        for (int g = 0; g < 4; g++)
            #pragma unroll
            for (int b = 0; b < 8; b++) acc[g][b] = 0.f;

        int kbase = ks * 33;
        #pragma unroll
        for (int j = 0; j < 32; j++) {
            float hb[8];
            #pragma unroll
            for (int b = 0; b < 8; b++) hb[b] = hs[b][kbase + j];
            #pragma unroll
            for (int g = 0; g < 4; g++)
                #pragma unroll
                for (int b = 0; b < 8; b++)
                    acc[g][b] += w[g][j] * hb[b];
        }

        // ---- butterfly reduce over the 16 k-slices (16-lane groups) ----
        #pragma unroll
        for (int g = 0; g < 4; g++)
            #pragma unroll
            for (int b = 0; b < 8; b++) {
                float v = acc[g][b];
                v += __shfl_xor(v, 1);
                v += __shfl_xor(v, 2);
                v += __shfl_xor(v, 4);
                v += __shfl_xor(v, 8);
                acc[g][b] = v;
            }

        // ---- finalize: lane ks<8 owns (D, batch=ks) ----
        if (ks < 8) {
            int b = ks;
            float x0 = xs[b][0], x1 = xs[b][1], x2 = xs[b][2];
            float x3 = xs[b][3], x4 = xs[b][4], x5 = xs[b][5];
            float pi = acc[0][b] + x0*wi[0][0] + x1*wi[0][1] + x2*wi[0][2]
                                 + x3*wi[0][3] + x4*wi[0][4] + x5*wi[0][5] + bs[0];
            float pf = acc[1][b] + x0*wi[1][0] + x1*wi[1][1] + x2*wi[1][2]
                                 + x3*wi[1][3] + x4*wi[1][4] + x5*wi[1][5] + bs[1];
            float pg = acc[2][b] + x0*wi[2][0] + x1*wi[2][1] + x2*wi[2][2]
                                 + x3*wi[2][3] + x4*wi[2][4] + x5*wi[2][5] + bs[2];
            float po = acc[3][b] + x0*wi[3][0] + x1*wi[3][1] + x2*wi[3][2]
                                 + x3*wi[3][3] + x4*wi[3][4] + x5*wi[3][5] + bs[3];
            float ig = 1.f / (1.f + __expf(-pi));
            float fg = 1.f / (1.f + __expf(-pf));
            float gg = tanhf(pg);
            float og = 1.f / (1.f + __expf(-po));
            c = fg * c + ig * gg;
            float hn = og * tanhf(c);
            __hip_atomic_store(&hout[(bG * 8 + b) * 512 + D], hn,
                               __ATOMIC_RELAXED, __HIP_MEMORY_SCOPE_AGENT);
            xT[((long long)t * 512 + D) * 64 + (bG * 8 + b)] = hn;
            // h stores must be at the coherence point before arrival.
            asm volatile("s_waitcnt vmcnt(0)" ::: "memory");
        }
        __syncthreads();   // all owners' stores landed

        if (t < TT - 1) {
            if (tid == 0) {
                __hip_atomic_fetch_add(&root[t * 8 + bG], 1u,
                    __ATOMIC_RELAXED, __HIP_MEMORY_SCOPE_AGENT);
                unsigned tries = 0;
                while (__hip_atomic_load(&root[t * 8 + bG], __ATOMIC_RELAXED,
                                         __HIP_MEMORY_SCOPE_AGENT) < 32u) {
                    __builtin_amdgcn_s_sleep(2);
                    if (++tries > 100000000u) break;   // fail loudly, never wedge
                }
            }
            __syncthreads();   // release whole block into step t+1
        }
    }
}

// ---------------------------------------------------------------------------
// Transpose xT[t][d][b] -> XB[b][t][d] bf16
// ---------------------------------------------------------------------------
__global__ __launch_bounds__(256) void transpose_k(
    const float* __restrict__ xT, unsigned short* __restrict__ XB_)
{
    __shared__ float tile[64][65];
    int dc = blockIdx.x, t = blockIdx.y;
    int tid = threadIdx.x;
    int bcol = tid & 63, grp = tid >> 6;
    #pragma unroll
    for (int j = 0; j < 16; j++) {
        int i = grp * 16 + j;
        tile[i][bcol] = xT[((long long)t * 512 + dc * 64 + i) * 64 + bcol];
    }
    __syncthreads();
    #pragma unroll
    for (int j = 0; j < 16; j++) {
        int brow = grp * 16 + j;
        float v = tile[bcol][brow];
        long long idx = ((long long)brow * TT + t) * DD + dc * 64 + bcol;
        XB_[idx] = f2bf(v);
    }
}

// ---------------------------------------------------------------------------
// Softmax over last dim (512), in-place on bf16 scores. One wave per row.
// ---------------------------------------------------------------------------
__global__ __launch_bounds__(256) void softmax_k(unsigned short* __restrict__ S)
{
    long long row = (long long)blockIdx.x * 4 + (threadIdx.x >> 6);
    int lane = threadIdx.x & 63;
    unsigned short* p = S + row * 512 + lane * 8;
    uint4 raw = *(const uint4*)p;
    unsigned short* u = (unsigned short*)&raw;
    float v[8];
    float m = -1e30f;
    #pragma unroll
    for (int j = 0; j < 8; j++) { v[j] = bf2f(u[j]); m = fmaxf(m, v[j]); }
    #pragma unroll
    for (int off = 1; off < 64; off <<= 1) m = fmaxf(m, __shfl_xor(m, off));
    float s = 0.f;
    #pragma unroll
    for (int j = 0; j < 8; j++) { v[j] = __expf(v[j] - m); s += v[j]; }
    #pragma unroll
    for (int off = 1; off < 64; off <<= 1) s += __shfl_xor(s, off);
    float inv = 1.f / s;
    unsigned int pk[4];
    #pragma unroll
    for (int j = 0; j < 4; j++)
        pk[j] = (unsigned int)f2bf(v[2 * j] * inv) | ((unsigned int)f2bf(v[2 * j + 1] * inv) << 16);
    *(uint4*)p = make_uint4(pk[0], pk[1], pk[2], pk[3]);
}

// ---------------------------------------------------------------------------
// Residual + LayerNorm: XB = LN(XB + Y)*g + b  (bf16 residual stream).
// ---------------------------------------------------------------------------
__global__ __launch_bounds__(256) void ln_k(
    unsigned short* XB_, const float* __restrict__ Y_,
    const float* __restrict__ g, const float* __restrict__ b2)
{
    long long row = (long long)blockIdx.x * 4 + (threadIdx.x >> 6);
    int lane = threadIdx.x & 63;
    long long base = row * 512 + lane * 8;
    float s[8];
    {
        uint4 xr = *(const uint4*)&XB_[base];
        const unsigned short* xu = (const unsigned short*)&xr;
        float4 y0 = *(const float4*)&Y_[base];
        float4 y1 = *(const float4*)&Y_[base + 4];
        s[0] = bf2f(xu[0]) + y0.x; s[1] = bf2f(xu[1]) + y0.y;
        s[2] = bf2f(xu[2]) + y0.z; s[3] = bf2f(xu[3]) + y0.w;
        s[4] = bf2f(xu[4]) + y1.x; s[5] = bf2f(xu[5]) + y1.y;
        s[6] = bf2f(xu[6]) + y1.z; s[7] = bf2f(xu[7]) + y1.w;
    }
    float sm = 0.f, sq = 0.f;
    #pragma unroll
    for (int j = 0; j < 8; j++) { sm += s[j]; sq += s[j] * s[j]; }
    #pragma unroll
    for (int off = 1; off < 64; off <<= 1) {
        sm += __shfl_xor(sm, off);
        sq += __shfl_xor(sq, off);
    }
    float mean = sm * (1.f / 512.f);
    float var = sq * (1.f / 512.f) - mean * mean;
    float rstd = rsqrtf(var + 1e-5f);
    int col = lane * 8;
    float o[8];
    #pragma unroll
    for (int j = 0; j < 8; j++) o[j] = (s[j] - mean) * rstd * g[col + j] + b2[col + j];
    unsigned int pk[4];
    #pragma unroll
    for (int j = 0; j < 4; j++)
        pk[j] = (unsigned int)f2bf(o[2 * j]) | ((unsigned int)f2bf(o[2 * j + 1]) << 16);
    *(uint4*)&XB_[base] = make_uint4(pk[0], pk[1], pk[2], pk[3]);
}

// ---------------------------------------------------------------------------
// Heads: garch_base + gate * ai_residual. One block per batch.
// ---------------------------------------------------------------------------
__global__ __launch_bounds__(128) void head_k(
    const unsigned short* __restrict__ XB_, const float* __restrict__ xe,
    const float* __restrict__ vol,
    const float* __restrict__ rh_w, const float* __restrict__ rh_b,
    const float* __restrict__ g1_w, const float* __restrict__ g1_b,
    const float* __restrict__ g2_w, const float* __restrict__ g2_b,
    const float* __restrict__ gp_w, const float* __restrict__ gp_b,
    float* __restrict__ out)
{
    int b = blockIdx.x, t = threadIdx.x;
    __shared__ float xl[512];
    __shared__ float hid[256];
    for (int j = t; j < 512; j += 128)
        xl[j] = bf2f(XB_[((long long)b * TT + (TT - 1)) * DD + j]);
    float gin[7];
    #pragma unroll
    for (int e = 0; e < 6; e++) gin[e] = xe[((long long)b * TT + (TT - 1)) * EE + e];
    gin[6] = vol[b];
    for (int j = t; j < 256; j += 128) {
        float s = g1_b[j];
        #pragma unroll
        for (int e = 0; e < 7; e++) s += g1_w[j * 7 + e] * gin[e];
        hid[j] = fmaxf(s, 0.f);
    }
    __syncthreads();
    for (int p = t; p < 96; p += 128) {
        float ai = rh_b[p];
        for (int j = 0; j < 512; j++) ai += xl[j] * rh_w[p * 512 + j];
        float gs = g2_b[p];
        for (int j = 0; j < 256; j++) gs += hid[j] * g2_w[p * 256 + j];
        float gate = 1.f / (1.f + expf(-gs));
        out[b * PP + p] = vol[b] * gp_w[p] + gp_b[p] + gate * ai;
    }
}

// ---------------------------------------------------------------------------
// Launch.  Workspace layout (bytes, total ~147.2 MB):
//   XB   bf16 residual  @ 0           (33554432)
//   Y    fp32 branch    @ 33554432    (67108864)   [aliases LSTM xT]
//   CH   chunk region   @ 100663296   (33554432)
//        QKVc @ +0 | SCc @ +12582912 | CTXc @ +29360128 ; HIDc @ +0 [FFN]
//   WB   bf16 weights   @ 134217728   (12582912)
//   HT0/HT1 h[b][d]     @ 146800640   (2 x 131072)
//   BAR  barrier slots  @ 147062784   (root 512x8 u32 = 16384)
//   VOL                 @ 147193856   (256)
// ---------------------------------------------------------------------------
extern "C" void kernel_launch(void* const* d_in, const int* in_sizes, int n_in,
                              void* d_out, int out_size, void* d_ws, size_t ws_size,
                              hipStream_t stream)
{
    const float* x_enc      = (const float*)d_in[0];
    const float* omega      = (const float*)d_in[4];
    const float* alpha      = (const float*)d_in[5];
    const float* beta       = (const float*)d_in[6];
    const float* gp_w       = (const float*)d_in[7];
    const float* gp_b       = (const float*)d_in[8];
    const float* w_ih       = (const float*)d_in[9];
    const float* w_hh       = (const float*)d_in[10];
    const float* b_ih       = (const float*)d_in[11];
    const float* b_hh       = (const float*)d_in[12];
    const float* attn_in_w  = (const float*)d_in[13];
    const float* attn_in_b  = (const float*)d_in[14];
    const float* attn_out_w = (const float*)d_in[15];
    const float* attn_out_b = (const float*)d_in[16];
    const float* ln1_g      = (const float*)d_in[17];
    const float* ln1_b      = (const float*)d_in[18];
    const float* ffn_w1     = (const float*)d_in[19];
    const float* ffn_b1     = (const float*)d_in[20];
    const float* ffn_w2     = (const float*)d_in[21];
    const float* ffn_b2     = (const float*)d_in[22];
    const float* ln2_g      = (const float*)d_in[23];
    const float* ln2_b      = (const float*)d_in[24];
    const float* rh_w       = (const float*)d_in[25];
    const float* rh_b       = (const float*)d_in[26];
    const float* g1_w       = (const float*)d_in[27];
    const float* g1_b       = (const float*)d_in[28];
    const float* g2_w       = (const float*)d_in[29];
    const float* g2_b       = (const float*)d_in[30];

    char* ws = (char*)d_ws;
    unsigned short* XB   = (unsigned short*)(ws + 0);
    float*          Y    = (float*)(ws + 33554432LL);
    float*          XT   = Y;
    unsigned short* QKVc = (unsigned short*)(ws + 100663296LL);
    unsigned short* SCc  = (unsigned short*)(ws + 113246208LL);
    unsigned short* CTXc = (unsigned short*)(ws + 130023424LL);
    unsigned short* HIDc = (unsigned short*)(ws + 100663296LL);
    unsigned short* WATI = (unsigned short*)(ws + 134217728LL);
    unsigned short* WATO = WATI + 1572864;
    unsigned short* WF1  = WATI + 2097152;
    unsigned short* WF2  = WATI + 4194304;
    float*          HT0  = (float*)(ws + 146800640LL);
    float*          HT1  = (float*)(ws + 146931712LL);
    unsigned*       ROOT = (unsigned*)(ws + 147062784LL);
    float*          VOL  = (float*)(ws + 147193856LL);

    hipMemsetAsync(HT0, 0, 131072, stream);
    hipMemsetAsync(ROOT, 0, 16384, stream);

    cvt_k<<<2048, 256, 0, stream>>>(attn_in_w,  WATI, 1572864);
    cvt_k<<<1024, 256, 0, stream>>>(attn_out_w, WATO, 524288);
    cvt_k<<<2048, 256, 0, stream>>>(ffn_w1,     WF1,  2097152);
    cvt_k<<<2048, 256, 0, stream>>>(ffn_w2,     WF2,  2097152);

    garch_k<<<1, 64, 0, stream>>>(x_enc, omega, alpha, beta, VOL);

    // Persistent LSTM v5: batch-partitioned, weights-in-registers.
    lstm_wreg_k<<<256, 256, 0, stream>>>(x_enc, w_hh, w_ih, b_ih, b_hh,
                                         HT0, HT1, XT, ROOT);

    transpose_k<<<dim3(8, 512, 1), 256, 0, stream>>>(XT, XB);

    for (int l = 0; l < 2; l++) {
        // Attention, chunked over batches: 8 chunks x 8 batches (4096 rows)
        for (int c = 0; c < 8; c++) {
            long long rowOff = (long long)c * 8 * 512;
            gemm_bt<false, true, false, true><<<dim3(32, 12, 1), 256, 0, stream>>>(
                XB + rowOff * 512, 512, 0, 0,
                WATI + l * 786432, 512, 0, 0, attn_in_b + l * 1536,
                QKVc, 1536, 0, 0, 512, 1, 1.0f);
            gemm_bt<false, false, false, true><<<dim3(4, 4, 32), 256, 0, stream>>>(
                QKVc, 1536, 786432LL, 128LL, QKVc + 512, 1536, 786432LL, 128LL, nullptr,
                SCc, 512, 1048576LL, 262144LL, 128, 4, 0.088388347648318447f);
            softmax_k<<<4096, 256, 0, stream>>>(SCc);
            gemm_bt<true, false, false, true><<<dim3(4, 1, 32), 256, 0, stream>>>(
                SCc, 512, 1048576LL, 262144LL, QKVc + 1024, 1536, 786432LL, 128LL, nullptr,
                CTXc, 512, 262144LL, 128LL, 512, 4, 1.0f);
            gemm_bt<false, true, false, false><<<dim3(32, 4, 1), 256, 0, stream>>>(
                CTXc, 512, 0, 0, WATO + l * 262144, 512, 0, 0, attn_out_b + l * 512,
                Y + rowOff * 512, 512, 0, 0, 512, 1, 1.0f);
        }
        ln_k<<<8192, 256, 0, stream>>>(XB, Y, ln1_g + l * 512, ln1_b + l * 512);

        // FFN, chunked over rows: 4 chunks x 8192 rows
        for (int mc = 0; mc < 4; mc++) {
            long long rowOff = (long long)mc * 8192;
            gemm_bt<false, true, true, true><<<dim3(64, 16, 1), 256, 0, stream>>>(
                XB + rowOff * 512, 512, 0, 0,
                WF1 + l * 1048576, 512, 0, 0, ffn_b1 + l * 2048,
                HIDc, 2048, 0, 0, 512, 1, 1.0f);
            gemm_bt<false, true, false, false><<<dim3(64, 4, 1), 256, 0, stream>>>(
                HIDc, 2048, 0, 0, WF2 + l * 1048576, 2048, 0, 0, ffn_b2 + l * 512,
                Y + rowOff * 512, 512, 0, 0, 2048, 1, 1.0f);
        }
        ln_k<<<8192, 256, 0, stream>>>(XB, Y, ln2_g + l * 512, ln2_b + l * 512);
    }

    head_k<<<64, 128, 0, stream>>>(XB, x_enc, VOL, rh_w, rh_b,
                                   g1_w, g1_b, g2_w, g2_b, gp_w, gp_b,
                                   (float*)d_out);
}

// Round 6
// 7856.973 us; speedup vs baseline: 3.0004x; 1.9197x over previous
//
#include <hip/hip_runtime.h>
#include <hip/hip_bf16.h>

// Model dims
#define BB 64
#define TT 512
#define DD 512
#define EE 6
#define PP 96
#define NHH 4
#define HDD 128
#define FFF 2048

typedef short bf16x8 __attribute__((ext_vector_type(8)));
typedef float f32x4 __attribute__((ext_vector_type(4)));

__device__ __forceinline__ float bf2f(unsigned short u) {
    unsigned int x = ((unsigned int)u) << 16;
    return __uint_as_float(x);
}
__device__ __forceinline__ unsigned short f2bf(float f) {
    __hip_bfloat16 h = __float2bfloat16(f);
    return *reinterpret_cast<unsigned short*>(&h);
}

// ---------------------------------------------------------------------------
// Generic MFMA GEMM:  C[m][n] = alpha * sum_k A[m][k] * W[n][k]  (+bias[n])
// 128x128 tile, BK=32, 256 threads (4 waves, each a 64x64 quadrant of
// 4x4 mfma_f32_16x16x32_bf16). TRANSW stages W[k*ldw+n] (V^T for P·V).
// Batched via blockIdx.z -> (b = z/Hdiv, h = z%Hdiv) offsets.
// ---------------------------------------------------------------------------
template<bool TRANSW, bool BIAS, bool RELU, bool OUTBF16>
__global__ __launch_bounds__(256) void gemm_bt(
    const unsigned short* __restrict__ A, int lda, long long aB, long long aH,
    const unsigned short* __restrict__ W, int ldw, long long wB, long long wH,
    const float* __restrict__ bias,
    void* __restrict__ Cv, int ldc, long long cB, long long cH,
    int K, int Hdiv, float alpha)
{
    __shared__ unsigned short As[128 * 40];
    __shared__ unsigned short Ws[128 * 40];
    int t = threadIdx.x;
    int z = blockIdx.z;
    int zb = z / Hdiv, zh = z - zb * Hdiv;
    long long aOff = (long long)zb * aB + (long long)zh * aH;
    long long wOff = (long long)zb * wB + (long long)zh * wH;
    long long cOff = (long long)zb * cB + (long long)zh * cH;
    int m0 = blockIdx.x * 128, n0 = blockIdx.y * 128;

    int arow = t >> 1, acol = (t & 1) * 16;
    const unsigned short* Ag = A + aOff + (long long)(m0 + arow) * lda + acol;
    const unsigned short* WgN = W + wOff + (long long)(n0 + arow) * ldw + acol;
    int wk = t >> 3, wn = (t & 7) * 16;
    const unsigned short* WgT = W + wOff + n0 + wn;

    int wave = t >> 6, lane = t & 63;
    int wm = (wave & 1) * 64, wn2 = (wave >> 1) * 64;
    int lrow = lane & 15, quad = lane >> 4;

    f32x4 acc[4][4];
    #pragma unroll
    for (int i = 0; i < 4; i++)
        #pragma unroll
        for (int j = 0; j < 4; j++)
            acc[i][j] = (f32x4){0.f, 0.f, 0.f, 0.f};

    for (int k0 = 0; k0 < K; k0 += 32) {
        __syncthreads();
        {
            uint4 a0 = *(const uint4*)(Ag + k0);
            uint4 a1 = *(const uint4*)(Ag + k0 + 8);
            *(uint4*)&As[arow * 40 + acol] = a0;
            *(uint4*)&As[arow * 40 + acol + 8] = a1;
            if (!TRANSW) {
                uint4 w0 = *(const uint4*)(WgN + k0);
                uint4 w1 = *(const uint4*)(WgN + k0 + 8);
                *(uint4*)&Ws[arow * 40 + acol] = w0;
                *(uint4*)&Ws[arow * 40 + acol + 8] = w1;
            } else {
                const unsigned short* p = WgT + (long long)(k0 + wk) * ldw;
                uint4 w0 = *(const uint4*)(p);
                uint4 w1 = *(const uint4*)(p + 8);
                const unsigned short* s0 = (const unsigned short*)&w0;
                const unsigned short* s1 = (const unsigned short*)&w1;
                #pragma unroll
                for (int j = 0; j < 8; j++) Ws[(wn + j) * 40 + wk] = s0[j];
                #pragma unroll
                for (int j = 0; j < 8; j++) Ws[(wn + 8 + j) * 40 + wk] = s1[j];
            }
        }
        __syncthreads();
        bf16x8 af[4], bf[4];
        #pragma unroll
        for (int i = 0; i < 4; i++)
            af[i] = *(const bf16x8*)&As[(wm + i * 16 + lrow) * 40 + quad * 8];
        #pragma unroll
        for (int j = 0; j < 4; j++)
            bf[j] = *(const bf16x8*)&Ws[(wn2 + j * 16 + lrow) * 40 + quad * 8];
        #pragma unroll
        for (int i = 0; i < 4; i++)
            #pragma unroll
            for (int j = 0; j < 4; j++)
                acc[i][j] = __builtin_amdgcn_mfma_f32_16x16x32_bf16(af[i], bf[j], acc[i][j], 0, 0, 0);
    }

    #pragma unroll
    for (int i = 0; i < 4; i++) {
        #pragma unroll
        for (int j = 0; j < 4; j++) {
            #pragma unroll
            for (int r = 0; r < 4; r++) {
                int row = m0 + wm + i * 16 + quad * 4 + r;
                int col = n0 + wn2 + j * 16 + lrow;
                float v = acc[i][j][r] * alpha;
                if (BIAS) v += bias[col];
                if (RELU) v = fmaxf(v, 0.f);
                long long idx = cOff + (long long)row * ldc + col;
                if (OUTBF16) ((unsigned short*)Cv)[idx] = f2bf(v);
                else         ((float*)Cv)[idx] = v;
            }
        }
    }
}

// ---------------------------------------------------------------------------
__global__ void cvt_k(const float* __restrict__ in, unsigned short* __restrict__ out, int n)
{
    int i = blockIdx.x * 256 + threadIdx.x;
    int stride = gridDim.x * 256;
    for (; i < n; i += stride) out[i] = f2bf(in[i]);
}

// ---------------------------------------------------------------------------
// GARCH: per-batch variance + 511-step scalar recurrence. 1 block, lane = batch.
// ---------------------------------------------------------------------------
__global__ __launch_bounds__(64) void garch_k(
    const float* __restrict__ xe, const float* __restrict__ omega,
    const float* __restrict__ alpha, const float* __restrict__ beta,
    float* __restrict__ vol)
{
    int b = threadIdx.x;
    float sm = 0.f, sq = 0.f;
    for (int t2 = 0; t2 < TT; t2++) {
        float r = xe[((long long)b * TT + t2) * EE + 5];
        sm += r; sq += r * r;
    }
    float mean = sm / 512.f;
    float var = (sq - 512.f * mean * mean) / 511.f;
    float h = var + 1e-6f;
    float om = log1pf(expf(omega[0]));
    float al = 0.2f / (1.f + expf(-alpha[0]));
    float be = 0.8f / (1.f + expf(-beta[0]));
    for (int t2 = 0; t2 < TT - 1; t2++) {
        float r = xe[((long long)b * TT + t2) * EE + 5];
        h = om + al * r * r + be * h;
    }
    vol[b] = sqrtf(h);
}

// ---------------------------------------------------------------------------
// Persistent LSTM v6 — batch-partitioned, weights-in-registers, spill-free.
//
// Round-4 post-mortem: v5's w[4][32] (128 regs) + the allocator's 128-VGPR
// cap spilled the weight array to scratch -> 32 MB/step of HBM scratch
// reads (FETCH 18.2 GB) -> 25 us/step. Structure was correct (passed).
//
// v6 fixes the register budget:
//   512 threads/block: i = tid>>5 (16 dims), ks = tid&31 (32 k-slices of
//   16 k). w[4][16] = 64 VGPR. wi/bs moved to LDS (finalize-only reads).
//   Peak demand ~130 VGPR; __launch_bounds__(512,1) caps at 256 -> no spill.
// Everything else is v5's proven structure:
//   grid 256 = 32 dim-groups x 8 batch-groups; block stages only ITS 8
//   batches' h (16 KB, one coherent burst of 8 loads/thread); outer-product
//   4 gates x 8 batches; butterfly reduce over 32 ks lanes (xor 1..16);
//   lanes ks<8 finalize (D, b=ks) with reg c-state; per-column barrier
//   (relaxed AGENT atomics + vmcnt(0), tries-breakout).
// LDS ~19 KB. Padded hs: k -> k + (k>>5); 32 ks lanes hit 32 distinct
// banks ((16ks+ks/2) mod 32 bijective); dim-pair halves broadcast.
// Deadlock-safe by capacity: VGPR<=256 -> >=1 block/CU, grid 256 <= 256.
// ---------------------------------------------------------------------------
__global__ __launch_bounds__(512, 1) void lstm_wreg2_k(
    const float* __restrict__ xe, const float* __restrict__ w_hh,
    const float* __restrict__ w_ih, const float* __restrict__ b_ih,
    const float* __restrict__ b_hh,
    float* __restrict__ h0, float* __restrict__ h1,
    float* __restrict__ xT,
    unsigned* __restrict__ root)
{
    __shared__ float hs[8][528];      // h[b][k + k/32] pad: conflict-free
    __shared__ float xs[8][8];        // x_t[b][e]
    __shared__ float wsx[16][4][6];   // w_ih slice for this dim group
    __shared__ float bsx[16][4];      // b_ih + b_hh

    int blk = blockIdx.x;             // 0..255
    int dgG = blk >> 3;               // 0..31 dim group
    int bG  = blk & 7;                // 0..7  batch group
    int tid = threadIdx.x;            // 0..511
    int i   = tid >> 5;               // 0..15 dim within group
    int ks  = tid & 31;               // 0..31 k-slice (16 k each)
    int D   = dgG * 16 + i;           // global dim 0..511

    // ---- permanent register-resident w_hh slice: w[gate][16] ----
    float w[4][16];
    #pragma unroll
    for (int g = 0; g < 4; g++) {
        const float* wr = w_hh + ((long long)(g * 512 + D)) * 512 + ks * 16;
        #pragma unroll
        for (int jj = 0; jj < 4; jj++) {
            float4 v = *(const float4*)(wr + jj * 4);
            w[g][jj * 4 + 0] = v.x; w[g][jj * 4 + 1] = v.y;
            w[g][jj * 4 + 2] = v.z; w[g][jj * 4 + 3] = v.w;
        }
    }
    // ---- x-projection weights/biases into LDS (finalize-only reads) ----
    for (int idx = tid; idx < 16 * 4 * 6; idx += 512) {
        int i2 = idx / 24, g = (idx / 6) % 4, e = idx % 6;
        wsx[i2][g][e] = w_ih[((g * 512) + (dgG * 16 + i2)) * 6 + e];
    }
    if (tid < 64) {
        int i2 = tid >> 2, g = tid & 3;
        int D2 = dgG * 16 + i2;
        bsx[i2][g] = b_ih[g * 512 + D2] + b_hh[g * 512 + D2];
    }
    float c = 0.f;   // cell state for (D, b=ks) on lanes ks<8

    for (int t = 0; t < TT; t++) {
        const float* hin  = (t & 1) ? h1 : h0;
        float*       hout = (t & 1) ? h0 : h1;

        // ---- stage h[8][512] (16 KB) via one burst of coherent loads ----
        float hv[8];
        #pragma unroll
        for (int jj = 0; jj < 8; jj++) {
            int flat = jj * 512 + tid;            // 0..4095
            int row = flat >> 9, k = flat & 511;
            hv[jj] = __hip_atomic_load(&hin[(bG * 8 + row) * 512 + k],
                                       __ATOMIC_RELAXED,
                                       __HIP_MEMORY_SCOPE_AGENT);
        }
        if (tid < 64 && (tid & 7) < 6) {
            int b = tid >> 3, e = tid & 7;
            xs[b][e] = xe[((long long)(bG * 8 + b) * TT + t) * EE + e];
        }
        #pragma unroll
        for (int jj = 0; jj < 8; jj++) {
            int flat = jj * 512 + tid;
            int row = flat >> 9, k = flat & 511;
            hs[row][k + (k >> 5)] = hv[jj];
        }
        __syncthreads();

        // ---- outer-product dot: acc[gate][batch] over this 16-k slice ----
        float acc[4][8];
        #pragma unroll
        for (int g = 0; g < 4; g++)
            #pragma unroll
            for (int b = 0; b < 8; b++) acc[g][b] = 0.f;

        int kbase = ks * 16 + (ks >> 1);   // padded base (no pad inside run)
        #pragma unroll
        for (int j = 0; j < 16; j++) {
            float hb[8];
            #pragma unroll
            for (int b = 0; b < 8; b++) hb[b] = hs[b][kbase + j];
            #pragma unroll
            for (int g = 0; g < 4; g++)
                #pragma unroll
                for (int b = 0; b < 8; b++)
                    acc[g][b] += w[g][j] * hb[b];
        }

        // ---- butterfly reduce over the 32 k-slices (32-lane groups) ----
        #pragma unroll
        for (int g = 0; g < 4; g++)
            #pragma unroll
            for (int b = 0; b < 8; b++) {
                float v = acc[g][b];
                v += __shfl_xor(v, 1);
                v += __shfl_xor(v, 2);
                v += __shfl_xor(v, 4);
                v += __shfl_xor(v, 8);
                v += __shfl_xor(v, 16);
                acc[g][b] = v;
            }

        // ---- finalize: lane ks<8 owns (D, batch=ks) ----
        if (ks < 8) {
            int b = ks;
            float x0 = xs[b][0], x1 = xs[b][1], x2 = xs[b][2];
            float x3 = xs[b][3], x4 = xs[b][4], x5 = xs[b][5];
            float pi = acc[0][b] + x0*wsx[i][0][0] + x1*wsx[i][0][1] + x2*wsx[i][0][2]
                                 + x3*wsx[i][0][3] + x4*wsx[i][0][4] + x5*wsx[i][0][5] + bsx[i][0];
            float pf = acc[1][b] + x0*wsx[i][1][0] + x1*wsx[i][1][1] + x2*wsx[i][1][2]
                                 + x3*wsx[i][1][3] + x4*wsx[i][1][4] + x5*wsx[i][1][5] + bsx[i][1];
            float pg = acc[2][b] + x0*wsx[i][2][0] + x1*wsx[i][2][1] + x2*wsx[i][2][2]
                                 + x3*wsx[i][2][3] + x4*wsx[i][2][4] + x5*wsx[i][2][5] + bsx[i][2];
            float po = acc[3][b] + x0*wsx[i][3][0] + x1*wsx[i][3][1] + x2*wsx[i][3][2]
                                 + x3*wsx[i][3][3] + x4*wsx[i][3][4] + x5*wsx[i][3][5] + bsx[i][3];
            float ig = 1.f / (1.f + __expf(-pi));
            float fg = 1.f / (1.f + __expf(-pf));
            float gg = tanhf(pg);
            float og = 1.f / (1.f + __expf(-po));
            c = fg * c + ig * gg;
            float hn = og * tanhf(c);
            __hip_atomic_store(&hout[(bG * 8 + b) * 512 + D], hn,
                               __ATOMIC_RELAXED, __HIP_MEMORY_SCOPE_AGENT);
            xT[((long long)t * 512 + D) * 64 + (bG * 8 + b)] = hn;
            // h stores must be at the coherence point before arrival.
            asm volatile("s_waitcnt vmcnt(0)" ::: "memory");
        }
        __syncthreads();   // all owners' stores landed

        if (t < TT - 1) {
            if (tid == 0) {
                __hip_atomic_fetch_add(&root[t * 8 + bG], 1u,
                    __ATOMIC_RELAXED, __HIP_MEMORY_SCOPE_AGENT);
                unsigned tries = 0;
                while (__hip_atomic_load(&root[t * 8 + bG], __ATOMIC_RELAXED,
                                         __HIP_MEMORY_SCOPE_AGENT) < 32u) {
                    __builtin_amdgcn_s_sleep(2);
                    if (++tries > 100000000u) break;   // fail loudly, never wedge
                }
            }
            __syncthreads();   // release whole block into step t+1
        }
    }
}

// ---------------------------------------------------------------------------
// Transpose xT[t][d][b] -> XB[b][t][d] bf16
// ---------------------------------------------------------------------------
__global__ __launch_bounds__(256) void transpose_k(
    const float* __restrict__ xT, unsigned short* __restrict__ XB_)
{
    __shared__ float tile[64][65];
    int dc = blockIdx.x, t = blockIdx.y;
    int tid = threadIdx.x;
    int bcol = tid & 63, grp = tid >> 6;
    #pragma unroll
    for (int j = 0; j < 16; j++) {
        int i = grp * 16 + j;
        tile[i][bcol] = xT[((long long)t * 512 + dc * 64 + i) * 64 + bcol];
    }
    __syncthreads();
    #pragma unroll
    for (int j = 0; j < 16; j++) {
        int brow = grp * 16 + j;
        float v = tile[bcol][brow];
        long long idx = ((long long)brow * TT + t) * DD + dc * 64 + bcol;
        XB_[idx] = f2bf(v);
    }
}

// ---------------------------------------------------------------------------
// Softmax over last dim (512), in-place on bf16 scores. One wave per row.
// ---------------------------------------------------------------------------
__global__ __launch_bounds__(256) void softmax_k(unsigned short* __restrict__ S)
{
    long long row = (long long)blockIdx.x * 4 + (threadIdx.x >> 6);
    int lane = threadIdx.x & 63;
    unsigned short* p = S + row * 512 + lane * 8;
    uint4 raw = *(const uint4*)p;
    unsigned short* u = (unsigned short*)&raw;
    float v[8];
    float m = -1e30f;
    #pragma unroll
    for (int j = 0; j < 8; j++) { v[j] = bf2f(u[j]); m = fmaxf(m, v[j]); }
    #pragma unroll
    for (int off = 1; off < 64; off <<= 1) m = fmaxf(m, __shfl_xor(m, off));
    float s = 0.f;
    #pragma unroll
    for (int j = 0; j < 8; j++) { v[j] = __expf(v[j] - m); s += v[j]; }
    #pragma unroll
    for (int off = 1; off < 64; off <<= 1) s += __shfl_xor(s, off);
    float inv = 1.f / s;
    unsigned int pk[4];
    #pragma unroll
    for (int j = 0; j < 4; j++)
        pk[j] = (unsigned int)f2bf(v[2 * j] * inv) | ((unsigned int)f2bf(v[2 * j + 1] * inv) << 16);
    *(uint4*)p = make_uint4(pk[0], pk[1], pk[2], pk[3]);
}

// ---------------------------------------------------------------------------
// Residual + LayerNorm: XB = LN(XB + Y)*g + b  (bf16 residual stream).
// ---------------------------------------------------------------------------
__global__ __launch_bounds__(256) void ln_k(
    unsigned short* XB_, const float* __restrict__ Y_,
    const float* __restrict__ g, const float* __restrict__ b2)
{
    long long row = (long long)blockIdx.x * 4 + (threadIdx.x >> 6);
    int lane = threadIdx.x & 63;
    long long base = row * 512 + lane * 8;
    float s[8];
    {
        uint4 xr = *(const uint4*)&XB_[base];
        const unsigned short* xu = (const unsigned short*)&xr;
        float4 y0 = *(const float4*)&Y_[base];
        float4 y1 = *(const float4*)&Y_[base + 4];
        s[0] = bf2f(xu[0]) + y0.x; s[1] = bf2f(xu[1]) + y0.y;
        s[2] = bf2f(xu[2]) + y0.z; s[3] = bf2f(xu[3]) + y0.w;
        s[4] = bf2f(xu[4]) + y1.x; s[5] = bf2f(xu[5]) + y1.y;
        s[6] = bf2f(xu[6]) + y1.z; s[7] = bf2f(xu[7]) + y1.w;
    }
    float sm = 0.f, sq = 0.f;
    #pragma unroll
    for (int j = 0; j < 8; j++) { sm += s[j]; sq += s[j] * s[j]; }
    #pragma unroll
    for (int off = 1; off < 64; off <<= 1) {
        sm += __shfl_xor(sm, off);
        sq += __shfl_xor(sq, off);
    }
    float mean = sm * (1.f / 512.f);
    float var = sq * (1.f / 512.f) - mean * mean;
    float rstd = rsqrtf(var + 1e-5f);
    int col = lane * 8;
    float o[8];
    #pragma unroll
    for (int j = 0; j < 8; j++) o[j] = (s[j] - mean) * rstd * g[col + j] + b2[col + j];
    unsigned int pk[4];
    #pragma unroll
    for (int j = 0; j < 4; j++)
        pk[j] = (unsigned int)f2bf(o[2 * j]) | ((unsigned int)f2bf(o[2 * j + 1]) << 16);
    *(uint4*)&XB_[base] = make_uint4(pk[0], pk[1], pk[2], pk[3]);
}

// ---------------------------------------------------------------------------
// Heads: garch_base + gate * ai_residual. One block per batch.
// ---------------------------------------------------------------------------
__global__ __launch_bounds__(128) void head_k(
    const unsigned short* __restrict__ XB_, const float* __restrict__ xe,
    const float* __restrict__ vol,
    const float* __restrict__ rh_w, const float* __restrict__ rh_b,
    const float* __restrict__ g1_w, const float* __restrict__ g1_b,
    const float* __restrict__ g2_w, const float* __restrict__ g2_b,
    const float* __restrict__ gp_w, const float* __restrict__ gp_b,
    float* __restrict__ out)
{
    int b = blockIdx.x, t = threadIdx.x;
    __shared__ float xl[512];
    __shared__ float hid[256];
    for (int j = t; j < 512; j += 128)
        xl[j] = bf2f(XB_[((long long)b * TT + (TT - 1)) * DD + j]);
    float gin[7];
    #pragma unroll
    for (int e = 0; e < 6; e++) gin[e] = xe[((long long)b * TT + (TT - 1)) * EE + e];
    gin[6] = vol[b];
    for (int j = t; j < 256; j += 128) {
        float s = g1_b[j];
        #pragma unroll
        for (int e = 0; e < 7; e++) s += g1_w[j * 7 + e] * gin[e];
        hid[j] = fmaxf(s, 0.f);
    }
    __syncthreads();
    for (int p = t; p < 96; p += 128) {
        float ai = rh_b[p];
        for (int j = 0; j < 512; j++) ai += xl[j] * rh_w[p * 512 + j];
        float gs = g2_b[p];
        for (int j = 0; j < 256; j++) gs += hid[j] * g2_w[p * 256 + j];
        float gate = 1.f / (1.f + expf(-gs));
        out[b * PP + p] = vol[b] * gp_w[p] + gp_b[p] + gate * ai;
    }
}

// ---------------------------------------------------------------------------
// Launch.  Workspace layout (bytes, total ~147.2 MB):
//   XB   bf16 residual  @ 0           (33554432)
//   Y    fp32 branch    @ 33554432    (67108864)   [aliases LSTM xT]
//   CH   chunk region   @ 100663296   (33554432)
//        QKVc @ +0 | SCc @ +12582912 | CTXc @ +29360128 ; HIDc @ +0 [FFN]
//   WB   bf16 weights   @ 134217728   (12582912)
//   HT0/HT1 h[b][d]     @ 146800640   (2 x 131072)
//   BAR  barrier slots  @ 147062784   (root 512x8 u32 = 16384)
//   VOL                 @ 147193856   (256)
// ---------------------------------------------------------------------------
extern "C" void kernel_launch(void* const* d_in, const int* in_sizes, int n_in,
                              void* d_out, int out_size, void* d_ws, size_t ws_size,
                              hipStream_t stream)
{
    const float* x_enc      = (const float*)d_in[0];
    const float* omega      = (const float*)d_in[4];
    const float* alpha      = (const float*)d_in[5];
    const float* beta       = (const float*)d_in[6];
    const float* gp_w       = (const float*)d_in[7];
    const float* gp_b       = (const float*)d_in[8];
    const float* w_ih       = (const float*)d_in[9];
    const float* w_hh       = (const float*)d_in[10];
    const float* b_ih       = (const float*)d_in[11];
    const float* b_hh       = (const float*)d_in[12];
    const float* attn_in_w  = (const float*)d_in[13];
    const float* attn_in_b  = (const float*)d_in[14];
    const float* attn_out_w = (const float*)d_in[15];
    const float* attn_out_b = (const float*)d_in[16];
    const float* ln1_g      = (const float*)d_in[17];
    const float* ln1_b      = (const float*)d_in[18];
    const float* ffn_w1     = (const float*)d_in[19];
    const float* ffn_b1     = (const float*)d_in[20];
    const float* ffn_w2     = (const float*)d_in[21];
    const float* ffn_b2     = (const float*)d_in[22];
    const float* ln2_g      = (const float*)d_in[23];
    const float* ln2_b      = (const float*)d_in[24];
    const float* rh_w       = (const float*)d_in[25];
    const float* rh_b       = (const float*)d_in[26];
    const float* g1_w       = (const float*)d_in[27];
    const float* g1_b       = (const float*)d_in[28];
    const float* g2_w       = (const float*)d_in[29];
    const float* g2_b       = (const float*)d_in[30];

    char* ws = (char*)d_ws;
    unsigned short* XB   = (unsigned short*)(ws + 0);
    float*          Y    = (float*)(ws + 33554432LL);
    float*          XT   = Y;
    unsigned short* QKVc = (unsigned short*)(ws + 100663296LL);
    unsigned short* SCc  = (unsigned short*)(ws + 113246208LL);
    unsigned short* CTXc = (unsigned short*)(ws + 130023424LL);
    unsigned short* HIDc = (unsigned short*)(ws + 100663296LL);
    unsigned short* WATI = (unsigned short*)(ws + 134217728LL);
    unsigned short* WATO = WATI + 1572864;
    unsigned short* WF1  = WATI + 2097152;
    unsigned short* WF2  = WATI + 4194304;
    float*          HT0  = (float*)(ws + 146800640LL);
    float*          HT1  = (float*)(ws + 146931712LL);
    unsigned*       ROOT = (unsigned*)(ws + 147062784LL);
    float*          VOL  = (float*)(ws + 147193856LL);

    hipMemsetAsync(HT0, 0, 131072, stream);
    hipMemsetAsync(ROOT, 0, 16384, stream);

    cvt_k<<<2048, 256, 0, stream>>>(attn_in_w,  WATI, 1572864);
    cvt_k<<<1024, 256, 0, stream>>>(attn_out_w, WATO, 524288);
    cvt_k<<<2048, 256, 0, stream>>>(ffn_w1,     WF1,  2097152);
    cvt_k<<<2048, 256, 0, stream>>>(ffn_w2,     WF2,  2097152);

    garch_k<<<1, 64, 0, stream>>>(x_enc, omega, alpha, beta, VOL);

    // Persistent LSTM v6: batch-partitioned, weights-in-registers, no spill.
    lstm_wreg2_k<<<256, 512, 0, stream>>>(x_enc, w_hh, w_ih, b_ih, b_hh,
                                          HT0, HT1, XT, ROOT);

    transpose_k<<<dim3(8, 512, 1), 256, 0, stream>>>(XT, XB);

    for (int l = 0; l < 2; l++) {
        // Attention, chunked over batches: 8 chunks x 8 batches (4096 rows)
        for (int c = 0; c < 8; c++) {
            long long rowOff = (long long)c * 8 * 512;
            gemm_bt<false, true, false, true><<<dim3(32, 12, 1), 256, 0, stream>>>(
                XB + rowOff * 512, 512, 0, 0,
                WATI + l * 786432, 512, 0, 0, attn_in_b + l * 1536,
                QKVc, 1536, 0, 0, 512, 1, 1.0f);
            gemm_bt<false, false, false, true><<<dim3(4, 4, 32), 256, 0, stream>>>(
                QKVc, 1536, 786432LL, 128LL, QKVc + 512, 1536, 786432LL, 128LL, nullptr,
                SCc, 512, 1048576LL, 262144LL, 128, 4, 0.088388347648318447f);
            softmax_k<<<4096, 256, 0, stream>>>(SCc);
            gemm_bt<true, false, false, true><<<dim3(4, 1, 32), 256, 0, stream>>>(
                SCc, 512, 1048576LL, 262144LL, QKVc + 1024, 1536, 786432LL, 128LL, nullptr,
                CTXc, 512, 262144LL, 128LL, 512, 4, 1.0f);
            gemm_bt<false, true, false, false><<<dim3(32, 4, 1), 256, 0, stream>>>(
                CTXc, 512, 0, 0, WATO + l * 262144, 512, 0, 0, attn_out_b + l * 512,
                Y + rowOff * 512, 512, 0, 0, 512, 1, 1.0f);
        }
        ln_k<<<8192, 256, 0, stream>>>(XB, Y, ln1_g + l * 512, ln1_b + l * 512);

        // FFN, chunked over rows: 4 chunks x 8192 rows
        for (int mc = 0; mc < 4; mc++) {
            long long rowOff = (long long)mc * 8192;
            gemm_bt<false, true, true, true><<<dim3(64, 16, 1), 256, 0, stream>>>(
                XB + rowOff * 512, 512, 0, 0,
                WF1 + l * 1048576, 512, 0, 0, ffn_b1 + l * 2048,
                HIDc, 2048, 0, 0, 512, 1, 1.0f);
            gemm_bt<false, true, false, false><<<dim3(64, 4, 1), 256, 0, stream>>>(
                HIDc, 2048, 0, 0, WF2 + l * 1048576, 2048, 0, 0, ffn_b2 + l * 512,
                Y + rowOff * 512, 512, 0, 0, 2048, 1, 1.0f);
        }
        ln_k<<<8192, 256, 0, stream>>>(XB, Y, ln2_g + l * 512, ln2_b + l * 512);
    }

    head_k<<<64, 128, 0, stream>>>(XB, x_enc, VOL, rh_w, rh_b,
                                   g1_w, g1_b, g2_w, g2_b, gp_w, gp_b,
                                   (float*)d_out);
}

// Round 7
// 4396.992 us; speedup vs baseline: 5.3614x; 1.7869x over previous
//
#include <hip/hip_runtime.h>
#include <hip/hip_bf16.h>

// Model dims
#define BB 64
#define TT 512
#define DD 512
#define EE 6
#define PP 96
#define NHH 4
#define HDD 128
#define FFF 2048

typedef short bf16x8 __attribute__((ext_vector_type(8)));
typedef float f32x4 __attribute__((ext_vector_type(4)));

__device__ __forceinline__ float bf2f(unsigned short u) {
    unsigned int x = ((unsigned int)u) << 16;
    return __uint_as_float(x);
}
__device__ __forceinline__ unsigned short f2bf(float f) {
    __hip_bfloat16 h = __float2bfloat16(f);
    return *reinterpret_cast<unsigned short*>(&h);
}

// ---------------------------------------------------------------------------
// Generic MFMA GEMM:  C[m][n] = alpha * sum_k A[m][k] * W[n][k]  (+bias[n])
// 128x128 tile, BK=32, 256 threads (4 waves, each a 64x64 quadrant of
// 4x4 mfma_f32_16x16x32_bf16). TRANSW stages W[k*ldw+n] (V^T for P·V).
// Batched via blockIdx.z -> (b = z/Hdiv, h = z%Hdiv) offsets.
// ---------------------------------------------------------------------------
template<bool TRANSW, bool BIAS, bool RELU, bool OUTBF16>
__global__ __launch_bounds__(256) void gemm_bt(
    const unsigned short* __restrict__ A, int lda, long long aB, long long aH,
    const unsigned short* __restrict__ W, int ldw, long long wB, long long wH,
    const float* __restrict__ bias,
    void* __restrict__ Cv, int ldc, long long cB, long long cH,
    int K, int Hdiv, float alpha)
{
    __shared__ unsigned short As[128 * 40];
    __shared__ unsigned short Ws[128 * 40];
    int t = threadIdx.x;
    int z = blockIdx.z;
    int zb = z / Hdiv, zh = z - zb * Hdiv;
    long long aOff = (long long)zb * aB + (long long)zh * aH;
    long long wOff = (long long)zb * wB + (long long)zh * wH;
    long long cOff = (long long)zb * cB + (long long)zh * cH;
    int m0 = blockIdx.x * 128, n0 = blockIdx.y * 128;

    int arow = t >> 1, acol = (t & 1) * 16;
    const unsigned short* Ag = A + aOff + (long long)(m0 + arow) * lda + acol;
    const unsigned short* WgN = W + wOff + (long long)(n0 + arow) * ldw + acol;
    int wk = t >> 3, wn = (t & 7) * 16;
    const unsigned short* WgT = W + wOff + n0 + wn;

    int wave = t >> 6, lane = t & 63;
    int wm = (wave & 1) * 64, wn2 = (wave >> 1) * 64;
    int lrow = lane & 15, quad = lane >> 4;

    f32x4 acc[4][4];
    #pragma unroll
    for (int i = 0; i < 4; i++)
        #pragma unroll
        for (int j = 0; j < 4; j++)
            acc[i][j] = (f32x4){0.f, 0.f, 0.f, 0.f};

    for (int k0 = 0; k0 < K; k0 += 32) {
        __syncthreads();
        {
            uint4 a0 = *(const uint4*)(Ag + k0);
            uint4 a1 = *(const uint4*)(Ag + k0 + 8);
            *(uint4*)&As[arow * 40 + acol] = a0;
            *(uint4*)&As[arow * 40 + acol + 8] = a1;
            if (!TRANSW) {
                uint4 w0 = *(const uint4*)(WgN + k0);
                uint4 w1 = *(const uint4*)(WgN + k0 + 8);
                *(uint4*)&Ws[arow * 40 + acol] = w0;
                *(uint4*)&Ws[arow * 40 + acol + 8] = w1;
            } else {
                const unsigned short* p = WgT + (long long)(k0 + wk) * ldw;
                uint4 w0 = *(const uint4*)(p);
                uint4 w1 = *(const uint4*)(p + 8);
                const unsigned short* s0 = (const unsigned short*)&w0;
                const unsigned short* s1 = (const unsigned short*)&w1;
                #pragma unroll
                for (int j = 0; j < 8; j++) Ws[(wn + j) * 40 + wk] = s0[j];
                #pragma unroll
                for (int j = 0; j < 8; j++) Ws[(wn + 8 + j) * 40 + wk] = s1[j];
            }
        }
        __syncthreads();
        bf16x8 af[4], bf[4];
        #pragma unroll
        for (int i = 0; i < 4; i++)
            af[i] = *(const bf16x8*)&As[(wm + i * 16 + lrow) * 40 + quad * 8];
        #pragma unroll
        for (int j = 0; j < 4; j++)
            bf[j] = *(const bf16x8*)&Ws[(wn2 + j * 16 + lrow) * 40 + quad * 8];
        #pragma unroll
        for (int i = 0; i < 4; i++)
            #pragma unroll
            for (int j = 0; j < 4; j++)
                acc[i][j] = __builtin_amdgcn_mfma_f32_16x16x32_bf16(af[i], bf[j], acc[i][j], 0, 0, 0);
    }

    #pragma unroll
    for (int i = 0; i < 4; i++) {
        #pragma unroll
        for (int j = 0; j < 4; j++) {
            #pragma unroll
            for (int r = 0; r < 4; r++) {
                int row = m0 + wm + i * 16 + quad * 4 + r;
                int col = n0 + wn2 + j * 16 + lrow;
                float v = acc[i][j][r] * alpha;
                if (BIAS) v += bias[col];
                if (RELU) v = fmaxf(v, 0.f);
                long long idx = cOff + (long long)row * ldc + col;
                if (OUTBF16) ((unsigned short*)Cv)[idx] = f2bf(v);
                else         ((float*)Cv)[idx] = v;
            }
        }
    }
}

// ---------------------------------------------------------------------------
__global__ void cvt_k(const float* __restrict__ in, unsigned short* __restrict__ out, int n)
{
    int i = blockIdx.x * 256 + threadIdx.x;
    int stride = gridDim.x * 256;
    for (; i < n; i += stride) out[i] = f2bf(in[i]);
}

// ---------------------------------------------------------------------------
// GARCH: per-batch variance + 511-step scalar recurrence. 1 block, lane = batch.
// ---------------------------------------------------------------------------
__global__ __launch_bounds__(64) void garch_k(
    const float* __restrict__ xe, const float* __restrict__ omega,
    const float* __restrict__ alpha, const float* __restrict__ beta,
    float* __restrict__ vol)
{
    int b = threadIdx.x;
    float sm = 0.f, sq = 0.f;
    for (int t2 = 0; t2 < TT; t2++) {
        float r = xe[((long long)b * TT + t2) * EE + 5];
        sm += r; sq += r * r;
    }
    float mean = sm / 512.f;
    float var = (sq - 512.f * mean * mean) / 511.f;
    float h = var + 1e-6f;
    float om = log1pf(expf(omega[0]));
    float al = 0.2f / (1.f + expf(-alpha[0]));
    float be = 0.8f / (1.f + expf(-beta[0]));
    for (int t2 = 0; t2 < TT - 1; t2++) {
        float r = xe[((long long)b * TT + t2) * EE + 5];
        h = om + al * r * r + be * h;
    }
    vol[b] = sqrtf(h);
}

// ---------------------------------------------------------------------------
// Persistent LSTM v7 — halving butterfly + float2 LDS reads.
//
// Round-5 post-mortem: v6's 12us/step was DS-unit-bound: 160 shfl/thread
// butterfly (~3.2us) + 128 scalar ds_read_b32 (~2.5us). VALU (0.85us) and
// stage (~2us) were fine.
//
// v7 (same grid/partitioning/coherence as v6):
//  * Halving butterfly: 31 shfl instead of 160. At stage m (16,8,4,2,1):
//      send = (ks&m)? v[j] : v[j+n]; recv = shfl_xor(send,m);
//      v'[j] = ((ks&m)? v[j+n] : v[j]) + recv;
//    After 5 stages lane ks holds reduced slot ks = (g=ks>>3, b=ks&7).
//    Each lane applies its own gate's x-proj + activation; 4 shfl gathers
//    bring i/f/g/o to lane b (ks<8) for the c update.
//    part[] LDS and its __syncthreads are GONE (reduce is wave-internal).
//  * hs pad k + 2*(k>>5): 32 ks bases still on 32 distinct banks
//    (bijective mod 32; even/odd ks each cover all banks in pairs -> 2-way
//    = free), 16-run bases 8B-aligned -> 64 ds_read_b64 instead of 128 b32.
// Deadlock-safe by capacity unchanged; barrier primitives unchanged.
// ---------------------------------------------------------------------------
__global__ __launch_bounds__(512, 1) void lstm_wreg3_k(
    const float* __restrict__ xe, const float* __restrict__ w_hh,
    const float* __restrict__ w_ih, const float* __restrict__ b_ih,
    const float* __restrict__ b_hh,
    float* __restrict__ h0, float* __restrict__ h1,
    float* __restrict__ xT,
    unsigned* __restrict__ root)
{
    __shared__ float hs[8][544];      // h[b][k + 2*(k>>5)] (max 541)
    __shared__ float xs[8][8];        // x_t[b][e]
    __shared__ float wsx[16][4][6];   // w_ih slice for this dim group
    __shared__ float bsx[16][4];      // b_ih + b_hh

    int blk = blockIdx.x;             // 0..255
    int dgG = blk >> 3;               // 0..31 dim group
    int bG  = blk & 7;                // 0..7  batch group
    int tid = threadIdx.x;            // 0..511
    int i   = tid >> 5;               // 0..15 dim within group
    int ks  = tid & 31;               // 0..31 k-slice (16 k each)
    int D   = dgG * 16 + i;           // global dim 0..511
    int lane = tid & 63;
    int go  = lane & 32;              // 32-group base within wave

    // ---- permanent register-resident w_hh slice: w[gate][16] ----
    float w[4][16];
    #pragma unroll
    for (int g = 0; g < 4; g++) {
        const float* wr = w_hh + ((long long)(g * 512 + D)) * 512 + ks * 16;
        #pragma unroll
        for (int jj = 0; jj < 4; jj++) {
            float4 v4 = *(const float4*)(wr + jj * 4);
            w[g][jj * 4 + 0] = v4.x; w[g][jj * 4 + 1] = v4.y;
            w[g][jj * 4 + 2] = v4.z; w[g][jj * 4 + 3] = v4.w;
        }
    }
    // ---- x-projection weights/biases into LDS ----
    for (int idx = tid; idx < 16 * 4 * 6; idx += 512) {
        int i2 = idx / 24, g = (idx / 6) % 4, e = idx % 6;
        wsx[i2][g][e] = w_ih[((g * 512) + (dgG * 16 + i2)) * 6 + e];
    }
    if (tid < 64) {
        int i2 = tid >> 2, g = tid & 3;
        int D2 = dgG * 16 + i2;
        bsx[i2][g] = b_ih[g * 512 + D2] + b_hh[g * 512 + D2];
    }
    float c = 0.f;   // cell state for (D, b=ks) on lanes ks<8

    for (int t = 0; t < TT; t++) {
        const float* hin  = (t & 1) ? h1 : h0;
        float*       hout = (t & 1) ? h0 : h1;

        // ---- stage h[8][512] (16 KB) via one burst of coherent loads ----
        float hv[8];
        #pragma unroll
        for (int jj = 0; jj < 8; jj++) {
            int flat = jj * 512 + tid;            // 0..4095
            int row = flat >> 9, k = flat & 511;
            hv[jj] = __hip_atomic_load(&hin[(bG * 8 + row) * 512 + k],
                                       __ATOMIC_RELAXED,
                                       __HIP_MEMORY_SCOPE_AGENT);
        }
        if (tid < 64 && (tid & 7) < 6) {
            int b = tid >> 3, e = tid & 7;
            xs[b][e] = xe[((long long)(bG * 8 + b) * TT + t) * EE + e];
        }
        #pragma unroll
        for (int jj = 0; jj < 8; jj++) {
            int flat = jj * 512 + tid;
            int row = flat >> 9, k = flat & 511;
            hs[row][k + 2 * (k >> 5)] = hv[jj];
        }
        __syncthreads();

        // ---- outer-product dot: v[g*8+b] over this 16-k slice ----
        float v[32];
        #pragma unroll
        for (int s = 0; s < 32; s++) v[s] = 0.f;

        int kbase = ks * 16 + 2 * (ks >> 1);   // even -> 8B-aligned
        #pragma unroll
        for (int jj = 0; jj < 8; jj++) {
            float2 hb2[8];
            #pragma unroll
            for (int b = 0; b < 8; b++)
                hb2[b] = *(const float2*)&hs[b][kbase + jj * 2];
            #pragma unroll
            for (int g = 0; g < 4; g++)
                #pragma unroll
                for (int b = 0; b < 8; b++) {
                    v[g * 8 + b] += w[g][jj * 2]     * hb2[b].x;
                    v[g * 8 + b] += w[g][jj * 2 + 1] * hb2[b].y;
                }
        }

        // ---- halving butterfly over 32 lanes: lane ks ends with slot ks --
        float t16[16];
        #pragma unroll
        for (int j = 0; j < 16; j++) {
            float send = (ks & 16) ? v[j] : v[j + 16];
            float recv = __shfl_xor(send, 16);
            t16[j] = ((ks & 16) ? v[j + 16] : v[j]) + recv;
        }
        float t8[8];
        #pragma unroll
        for (int j = 0; j < 8; j++) {
            float send = (ks & 8) ? t16[j] : t16[j + 8];
            float recv = __shfl_xor(send, 8);
            t8[j] = ((ks & 8) ? t16[j + 8] : t16[j]) + recv;
        }
        float t4[4];
        #pragma unroll
        for (int j = 0; j < 4; j++) {
            float send = (ks & 4) ? t8[j] : t8[j + 4];
            float recv = __shfl_xor(send, 4);
            t4[j] = ((ks & 4) ? t8[j + 4] : t8[j]) + recv;
        }
        float t2[2];
        #pragma unroll
        for (int j = 0; j < 2; j++) {
            float send = (ks & 2) ? t4[j] : t4[j + 2];
            float recv = __shfl_xor(send, 2);
            t2[j] = ((ks & 2) ? t4[j + 2] : t4[j]) + recv;
        }
        float red;
        {
            float send = (ks & 1) ? t2[0] : t2[1];
            float recv = __shfl_xor(send, 1);
            red = ((ks & 1) ? t2[1] : t2[0]) + recv;
        }

        // ---- per-lane gate finalize: lane ks owns (g=ks>>3, b=ks&7) ----
        int gg_ = ks >> 3, bb_ = ks & 7;
        float x0 = xs[bb_][0], x1 = xs[bb_][1], x2 = xs[bb_][2];
        float x3 = xs[bb_][3], x4 = xs[bb_][4], x5 = xs[bb_][5];
        float p = red + x0 * wsx[i][gg_][0] + x1 * wsx[i][gg_][1]
                      + x2 * wsx[i][gg_][2] + x3 * wsx[i][gg_][3]
                      + x4 * wsx[i][gg_][4] + x5 * wsx[i][gg_][5]
                      + bsx[i][gg_];
        float sg = 1.f / (1.f + __expf(-p));
        float th = tanhf(p);
        float act = (gg_ == 2) ? th : sg;

        // gather i/f/g/o activations to lane b (all lanes execute shfl)
        float ai = __shfl(act, go + 0  + bb_);
        float af = __shfl(act, go + 8  + bb_);
        float ag = __shfl(act, go + 16 + bb_);
        float ao = __shfl(act, go + 24 + bb_);

        if (ks < 8) {
            int b = ks;
            c = af * c + ai * ag;
            float hn = ao * tanhf(c);
            __hip_atomic_store(&hout[(bG * 8 + b) * 512 + D], hn,
                               __ATOMIC_RELAXED, __HIP_MEMORY_SCOPE_AGENT);
            xT[((long long)t * 512 + D) * 64 + (bG * 8 + b)] = hn;
            // h stores must be at the coherence point before arrival.
            asm volatile("s_waitcnt vmcnt(0)" ::: "memory");
        }
        __syncthreads();   // all owners' stores landed; hs reads done

        if (t < TT - 1) {
            if (tid == 0) {
                __hip_atomic_fetch_add(&root[t * 8 + bG], 1u,
                    __ATOMIC_RELAXED, __HIP_MEMORY_SCOPE_AGENT);
                unsigned tries = 0;
                while (__hip_atomic_load(&root[t * 8 + bG], __ATOMIC_RELAXED,
                                         __HIP_MEMORY_SCOPE_AGENT) < 32u) {
                    __builtin_amdgcn_s_sleep(2);
                    if (++tries > 100000000u) break;   // fail loudly, never wedge
                }
            }
            __syncthreads();   // release whole block into step t+1
        }
    }
}

// ---------------------------------------------------------------------------
// Transpose xT[t][d][b] -> XB[b][t][d] bf16
// ---------------------------------------------------------------------------
__global__ __launch_bounds__(256) void transpose_k(
    const float* __restrict__ xT, unsigned short* __restrict__ XB_)
{
    __shared__ float tile[64][65];
    int dc = blockIdx.x, t = blockIdx.y;
    int tid = threadIdx.x;
    int bcol = tid & 63, grp = tid >> 6;
    #pragma unroll
    for (int j = 0; j < 16; j++) {
        int i = grp * 16 + j;
        tile[i][bcol] = xT[((long long)t * 512 + dc * 64 + i) * 64 + bcol];
    }
    __syncthreads();
    #pragma unroll
    for (int j = 0; j < 16; j++) {
        int brow = grp * 16 + j;
        float v = tile[bcol][brow];
        long long idx = ((long long)brow * TT + t) * DD + dc * 64 + bcol;
        XB_[idx] = f2bf(v);
    }
}

// ---------------------------------------------------------------------------
// Softmax over last dim (512), in-place on bf16 scores. One wave per row.
// ---------------------------------------------------------------------------
__global__ __launch_bounds__(256) void softmax_k(unsigned short* __restrict__ S)
{
    long long row = (long long)blockIdx.x * 4 + (threadIdx.x >> 6);
    int lane = threadIdx.x & 63;
    unsigned short* p = S + row * 512 + lane * 8;
    uint4 raw = *(const uint4*)p;
    unsigned short* u = (unsigned short*)&raw;
    float v[8];
    float m = -1e30f;
    #pragma unroll
    for (int j = 0; j < 8; j++) { v[j] = bf2f(u[j]); m = fmaxf(m, v[j]); }
    #pragma unroll
    for (int off = 1; off < 64; off <<= 1) m = fmaxf(m, __shfl_xor(m, off));
    float s = 0.f;
    #pragma unroll
    for (int j = 0; j < 8; j++) { v[j] = __expf(v[j] - m); s += v[j]; }
    #pragma unroll
    for (int off = 1; off < 64; off <<= 1) s += __shfl_xor(s, off);
    float inv = 1.f / s;
    unsigned int pk[4];
    #pragma unroll
    for (int j = 0; j < 4; j++)
        pk[j] = (unsigned int)f2bf(v[2 * j] * inv) | ((unsigned int)f2bf(v[2 * j + 1] * inv) << 16);
    *(uint4*)p = make_uint4(pk[0], pk[1], pk[2], pk[3]);
}

// ---------------------------------------------------------------------------
// Residual + LayerNorm: XB = LN(XB + Y)*g + b  (bf16 residual stream).
// ---------------------------------------------------------------------------
__global__ __launch_bounds__(256) void ln_k(
    unsigned short* XB_, const float* __restrict__ Y_,
    const float* __restrict__ g, const float* __restrict__ b2)
{
    long long row = (long long)blockIdx.x * 4 + (threadIdx.x >> 6);
    int lane = threadIdx.x & 63;
    long long base = row * 512 + lane * 8;
    float s[8];
    {
        uint4 xr = *(const uint4*)&XB_[base];
        const unsigned short* xu = (const unsigned short*)&xr;
        float4 y0 = *(const float4*)&Y_[base];
        float4 y1 = *(const float4*)&Y_[base + 4];
        s[0] = bf2f(xu[0]) + y0.x; s[1] = bf2f(xu[1]) + y0.y;
        s[2] = bf2f(xu[2]) + y0.z; s[3] = bf2f(xu[3]) + y0.w;
        s[4] = bf2f(xu[4]) + y1.x; s[5] = bf2f(xu[5]) + y1.y;
        s[6] = bf2f(xu[6]) + y1.z; s[7] = bf2f(xu[7]) + y1.w;
    }
    float sm = 0.f, sq = 0.f;
    #pragma unroll
    for (int j = 0; j < 8; j++) { sm += s[j]; sq += s[j] * s[j]; }
    #pragma unroll
    for (int off = 1; off < 64; off <<= 1) {
        sm += __shfl_xor(sm, off);
        sq += __shfl_xor(sq, off);
    }
    float mean = sm * (1.f / 512.f);
    float var = sq * (1.f / 512.f) - mean * mean;
    float rstd = rsqrtf(var + 1e-5f);
    int col = lane * 8;
    float o[8];
    #pragma unroll
    for (int j = 0; j < 8; j++) o[j] = (s[j] - mean) * rstd * g[col + j] + b2[col + j];
    unsigned int pk[4];
    #pragma unroll
    for (int j = 0; j < 4; j++)
        pk[j] = (unsigned int)f2bf(o[2 * j]) | ((unsigned int)f2bf(o[2 * j + 1]) << 16);
    *(uint4*)&XB_[base] = make_uint4(pk[0], pk[1], pk[2], pk[3]);
}

// ---------------------------------------------------------------------------
// Heads: garch_base + gate * ai_residual. One block per batch.
// ---------------------------------------------------------------------------
__global__ __launch_bounds__(128) void head_k(
    const unsigned short* __restrict__ XB_, const float* __restrict__ xe,
    const float* __restrict__ vol,
    const float* __restrict__ rh_w, const float* __restrict__ rh_b,
    const float* __restrict__ g1_w, const float* __restrict__ g1_b,
    const float* __restrict__ g2_w, const float* __restrict__ g2_b,
    const float* __restrict__ gp_w, const float* __restrict__ gp_b,
    float* __restrict__ out)
{
    int b = blockIdx.x, t = threadIdx.x;
    __shared__ float xl[512];
    __shared__ float hid[256];
    for (int j = t; j < 512; j += 128)
        xl[j] = bf2f(XB_[((long long)b * TT + (TT - 1)) * DD + j]);
    float gin[7];
    #pragma unroll
    for (int e = 0; e < 6; e++) gin[e] = xe[((long long)b * TT + (TT - 1)) * EE + e];
    gin[6] = vol[b];
    for (int j = t; j < 256; j += 128) {
        float s = g1_b[j];
        #pragma unroll
        for (int e = 0; e < 7; e++) s += g1_w[j * 7 + e] * gin[e];
        hid[j] = fmaxf(s, 0.f);
    }
    __syncthreads();
    for (int p = t; p < 96; p += 128) {
        float ai = rh_b[p];
        for (int j = 0; j < 512; j++) ai += xl[j] * rh_w[p * 512 + j];
        float gs = g2_b[p];
        for (int j = 0; j < 256; j++) gs += hid[j] * g2_w[p * 256 + j];
        float gate = 1.f / (1.f + expf(-gs));
        out[b * PP + p] = vol[b] * gp_w[p] + gp_b[p] + gate * ai;
    }
}

// ---------------------------------------------------------------------------
// Launch.  Workspace layout (bytes, total ~147.2 MB):
//   XB   bf16 residual  @ 0           (33554432)
//   Y    fp32 branch    @ 33554432    (67108864)   [aliases LSTM xT]
//   CH   chunk region   @ 100663296   (33554432)
//        QKVc @ +0 | SCc @ +12582912 | CTXc @ +29360128 ; HIDc @ +0 [FFN]
//   WB   bf16 weights   @ 134217728   (12582912)
//   HT0/HT1 h[b][d]     @ 146800640   (2 x 131072)
//   BAR  barrier slots  @ 147062784   (root 512x8 u32 = 16384)
//   VOL                 @ 147193856   (256)
// ---------------------------------------------------------------------------
extern "C" void kernel_launch(void* const* d_in, const int* in_sizes, int n_in,
                              void* d_out, int out_size, void* d_ws, size_t ws_size,
                              hipStream_t stream)
{
    const float* x_enc      = (const float*)d_in[0];
    const float* omega      = (const float*)d_in[4];
    const float* alpha      = (const float*)d_in[5];
    const float* beta       = (const float*)d_in[6];
    const float* gp_w       = (const float*)d_in[7];
    const float* gp_b       = (const float*)d_in[8];
    const float* w_ih       = (const float*)d_in[9];
    const float* w_hh       = (const float*)d_in[10];
    const float* b_ih       = (const float*)d_in[11];
    const float* b_hh       = (const float*)d_in[12];
    const float* attn_in_w  = (const float*)d_in[13];
    const float* attn_in_b  = (const float*)d_in[14];
    const float* attn_out_w = (const float*)d_in[15];
    const float* attn_out_b = (const float*)d_in[16];
    const float* ln1_g      = (const float*)d_in[17];
    const float* ln1_b      = (const float*)d_in[18];
    const float* ffn_w1     = (const float*)d_in[19];
    const float* ffn_b1     = (const float*)d_in[20];
    const float* ffn_w2     = (const float*)d_in[21];
    const float* ffn_b2     = (const float*)d_in[22];
    const float* ln2_g      = (const float*)d_in[23];
    const float* ln2_b      = (const float*)d_in[24];
    const float* rh_w       = (const float*)d_in[25];
    const float* rh_b       = (const float*)d_in[26];
    const float* g1_w       = (const float*)d_in[27];
    const float* g1_b       = (const float*)d_in[28];
    const float* g2_w       = (const float*)d_in[29];
    const float* g2_b       = (const float*)d_in[30];

    char* ws = (char*)d_ws;
    unsigned short* XB   = (unsigned short*)(ws + 0);
    float*          Y    = (float*)(ws + 33554432LL);
    float*          XT   = Y;
    unsigned short* QKVc = (unsigned short*)(ws + 100663296LL);
    unsigned short* SCc  = (unsigned short*)(ws + 113246208LL);
    unsigned short* CTXc = (unsigned short*)(ws + 130023424LL);
    unsigned short* HIDc = (unsigned short*)(ws + 100663296LL);
    unsigned short* WATI = (unsigned short*)(ws + 134217728LL);
    unsigned short* WATO = WATI + 1572864;
    unsigned short* WF1  = WATI + 2097152;
    unsigned short* WF2  = WATI + 4194304;
    float*          HT0  = (float*)(ws + 146800640LL);
    float*          HT1  = (float*)(ws + 146931712LL);
    unsigned*       ROOT = (unsigned*)(ws + 147062784LL);
    float*          VOL  = (float*)(ws + 147193856LL);

    hipMemsetAsync(HT0, 0, 131072, stream);
    hipMemsetAsync(ROOT, 0, 16384, stream);

    cvt_k<<<2048, 256, 0, stream>>>(attn_in_w,  WATI, 1572864);
    cvt_k<<<1024, 256, 0, stream>>>(attn_out_w, WATO, 524288);
    cvt_k<<<2048, 256, 0, stream>>>(ffn_w1,     WF1,  2097152);
    cvt_k<<<2048, 256, 0, stream>>>(ffn_w2,     WF2,  2097152);

    garch_k<<<1, 64, 0, stream>>>(x_enc, omega, alpha, beta, VOL);

    // Persistent LSTM v7: halving butterfly + float2 LDS reads.
    lstm_wreg3_k<<<256, 512, 0, stream>>>(x_enc, w_hh, w_ih, b_ih, b_hh,
                                          HT0, HT1, XT, ROOT);

    transpose_k<<<dim3(8, 512, 1), 256, 0, stream>>>(XT, XB);

    for (int l = 0; l < 2; l++) {
        // Attention, chunked over batches: 8 chunks x 8 batches (4096 rows)
        for (int c = 0; c < 8; c++) {
            long long rowOff = (long long)c * 8 * 512;
            gemm_bt<false, true, false, true><<<dim3(32, 12, 1), 256, 0, stream>>>(
                XB + rowOff * 512, 512, 0, 0,
                WATI + l * 786432, 512, 0, 0, attn_in_b + l * 1536,
                QKVc, 1536, 0, 0, 512, 1, 1.0f);
            gemm_bt<false, false, false, true><<<dim3(4, 4, 32), 256, 0, stream>>>(
                QKVc, 1536, 786432LL, 128LL, QKVc + 512, 1536, 786432LL, 128LL, nullptr,
                SCc, 512, 1048576LL, 262144LL, 128, 4, 0.088388347648318447f);
            softmax_k<<<4096, 256, 0, stream>>>(SCc);
            gemm_bt<true, false, false, true><<<dim3(4, 1, 32), 256, 0, stream>>>(
                SCc, 512, 1048576LL, 262144LL, QKVc + 1024, 1536, 786432LL, 128LL, nullptr,
                CTXc, 512, 262144LL, 128LL, 512, 4, 1.0f);
            gemm_bt<false, true, false, false><<<dim3(32, 4, 1), 256, 0, stream>>>(
                CTXc, 512, 0, 0, WATO + l * 262144, 512, 0, 0, attn_out_b + l * 512,
                Y + rowOff * 512, 512, 0, 0, 512, 1, 1.0f);
        }
        ln_k<<<8192, 256, 0, stream>>>(XB, Y, ln1_g + l * 512, ln1_b + l * 512);

        // FFN, chunked over rows: 4 chunks x 8192 rows
        for (int mc = 0; mc < 4; mc++) {
            long long rowOff = (long long)mc * 8192;
            gemm_bt<false, true, true, true><<<dim3(64, 16, 1), 256, 0, stream>>>(
                XB + rowOff * 512, 512, 0, 0,
                WF1 + l * 1048576, 512, 0, 0, ffn_b1 + l * 2048,
                HIDc, 2048, 0, 0, 512, 1, 1.0f);
            gemm_bt<false, true, false, false><<<dim3(64, 4, 1), 256, 0, stream>>>(
                HIDc, 2048, 0, 0, WF2 + l * 1048576, 2048, 0, 0, ffn_b2 + l * 512,
                Y + rowOff * 512, 512, 0, 0, 2048, 1, 1.0f);
        }
        ln_k<<<8192, 256, 0, stream>>>(XB, Y, ln2_g + l * 512, ln2_b + l * 512);
    }

    head_k<<<64, 128, 0, stream>>>(XB, x_enc, VOL, rh_w, rh_b,
                                   g1_w, g1_b, g2_w, g2_b, gp_w, gp_b,
                                   (float*)d_out);
}

// Round 8
// 4263.755 us; speedup vs baseline: 5.5289x; 1.0312x over previous
//
#include <hip/hip_runtime.h>
#include <hip/hip_bf16.h>

// Model dims
#define BB 64
#define TT 512
#define DD 512
#define EE 6
#define PP 96
#define NHH 4
#define HDD 128
#define FFF 2048

typedef short bf16x8 __attribute__((ext_vector_type(8)));
typedef float f32x4 __attribute__((ext_vector_type(4)));

__device__ __forceinline__ float bf2f(unsigned short u) {
    unsigned int x = ((unsigned int)u) << 16;
    return __uint_as_float(x);
}
__device__ __forceinline__ unsigned short f2bf(float f) {
    __hip_bfloat16 h = __float2bfloat16(f);
    return *reinterpret_cast<unsigned short*>(&h);
}

// Direct global->LDS 16B/lane async copy (gfx950). LDS base is WAVE-UNIFORM;
// HW adds lane*16. Global ptr is per-lane. (m97 pattern: +67% GEMM staging.)
__device__ __forceinline__ void gload_lds16(const unsigned short* g, unsigned short* l)
{
    __builtin_amdgcn_global_load_lds(
        (const __attribute__((address_space(1))) unsigned int*)g,
        (__attribute__((address_space(3))) unsigned int*)l, 16, 0, 0);
}

// ---------------------------------------------------------------------------
// Generic MFMA GEMM:  C[m][n] = alpha * sum_k A[m][k] * W[n][k]  (+bias[n])
// 128x128 tile, BK=32, 256 threads (4 waves, each a 64x64 quadrant of
// 4x4 mfma_f32_16x16x32_bf16).
// v7: A (and W when !TRANSW) staged via global_load_lds width-16 into
// LINEAR [128][32] LDS tiles — no reg round-trip, no staging ds_writes.
// Per wave, per operand, per K-step: 2 instrs cover 16 rows x 32 cols each.
// Linear LDS makes ds_read_b128 fragments 8-way bank-conflicted, but in
// this 2-barrier structure conflicts are off the critical path (T2 null in
// 128²+2ph regime, m228d/m230) — the vmcnt drain before s_barrier rules.
// TRANSW stages W[k*ldw+n] (V^T for P·V) via reg+scatter (unchanged logic).
// Batched via blockIdx.z -> (b = z/Hdiv, h = z%Hdiv) offsets.
// ---------------------------------------------------------------------------
template<bool TRANSW, bool BIAS, bool RELU, bool OUTBF16>
__global__ __launch_bounds__(256) void gemm_bt(
    const unsigned short* __restrict__ A, int lda, long long aB, long long aH,
    const unsigned short* __restrict__ W, int ldw, long long wB, long long wH,
    const float* __restrict__ bias,
    void* __restrict__ Cv, int ldc, long long cB, long long cH,
    int K, int Hdiv, float alpha)
{
    __shared__ unsigned short As[128 * 32];
    __shared__ unsigned short Ws[128 * 32];
    int t = threadIdx.x;
    int z = blockIdx.z;
    int zb = z / Hdiv, zh = z - zb * Hdiv;
    long long aOff = (long long)zb * aB + (long long)zh * aH;
    long long wOff = (long long)zb * wB + (long long)zh * wH;
    long long cOff = (long long)zb * cB + (long long)zh * cH;
    int m0 = blockIdx.x * 128, n0 = blockIdx.y * 128;

    int wave = t >> 6, lane = t & 63;

    // global_load_lds staging geometry: wave w covers rows [w*16, w*16+16)
    // (low chunk) and [64+w*16, ...) (high chunk); lane l -> row w*16+(l>>2),
    // col (l&3)*8. LDS bytes l*16 from the uniform chunk base = same cell.
    int srow = wave * 16 + (lane >> 2);
    int scol = (lane & 3) * 8;
    const unsigned short* AgL = A + aOff + (long long)(m0 + srow) * lda + scol;
    const unsigned short* AgH = A + aOff + (long long)(m0 + 64 + srow) * lda + scol;
    unsigned short* AsL = &As[(wave * 16) * 32];
    unsigned short* AsH = &As[(64 + wave * 16) * 32];
    const unsigned short* WgL = W + wOff + (long long)(n0 + srow) * ldw + scol;
    const unsigned short* WgH = W + wOff + (long long)(n0 + 64 + srow) * ldw + scol;
    unsigned short* WsL = &Ws[(wave * 16) * 32];
    unsigned short* WsH = &Ws[(64 + wave * 16) * 32];

    // TRANSW scatter-staging geometry (PV only)
    int wk = t >> 3, wn = (t & 7) * 16;
    const unsigned short* WgT = W + wOff + n0 + wn;

    int wm = (wave & 1) * 64, wn2 = (wave >> 1) * 64;
    int lrow = lane & 15, quad = lane >> 4;

    f32x4 acc[4][4];
    #pragma unroll
    for (int i = 0; i < 4; i++)
        #pragma unroll
        for (int j = 0; j < 4; j++)
            acc[i][j] = (f32x4){0.f, 0.f, 0.f, 0.f};

    for (int k0 = 0; k0 < K; k0 += 32) {
        __syncthreads();   // prior compute done reading LDS
        gload_lds16(AgL + k0, AsL);
        gload_lds16(AgH + k0, AsH);
        if (!TRANSW) {
            gload_lds16(WgL + k0, WsL);
            gload_lds16(WgH + k0, WsH);
        } else {
            const unsigned short* p = WgT + (long long)(k0 + wk) * ldw;
            uint4 w0 = *(const uint4*)(p);
            uint4 w1 = *(const uint4*)(p + 8);
            const unsigned short* s0 = (const unsigned short*)&w0;
            const unsigned short* s1 = (const unsigned short*)&w1;
            #pragma unroll
            for (int j = 0; j < 8; j++) Ws[(wn + j) * 32 + wk] = s0[j];
            #pragma unroll
            for (int j = 0; j < 8; j++) Ws[(wn + 8 + j) * 32 + wk] = s1[j];
        }
        __syncthreads();   // drains vmcnt(0) -> LDS tiles ready
        bf16x8 af[4], bf[4];
        #pragma unroll
        for (int i = 0; i < 4; i++)
            af[i] = *(const bf16x8*)&As[(wm + i * 16 + lrow) * 32 + quad * 8];
        #pragma unroll
        for (int j = 0; j < 4; j++)
            bf[j] = *(const bf16x8*)&Ws[(wn2 + j * 16 + lrow) * 32 + quad * 8];
        #pragma unroll
        for (int i = 0; i < 4; i++)
            #pragma unroll
            for (int j = 0; j < 4; j++)
                acc[i][j] = __builtin_amdgcn_mfma_f32_16x16x32_bf16(af[i], bf[j], acc[i][j], 0, 0, 0);
    }

    #pragma unroll
    for (int i = 0; i < 4; i++) {
        #pragma unroll
        for (int j = 0; j < 4; j++) {
            #pragma unroll
            for (int r = 0; r < 4; r++) {
                int row = m0 + wm + i * 16 + quad * 4 + r;
                int col = n0 + wn2 + j * 16 + lrow;
                float v = acc[i][j][r] * alpha;
                if (BIAS) v += bias[col];
                if (RELU) v = fmaxf(v, 0.f);
                long long idx = cOff + (long long)row * ldc + col;
                if (OUTBF16) ((unsigned short*)Cv)[idx] = f2bf(v);
                else         ((float*)Cv)[idx] = v;
            }
        }
    }
}

// ---------------------------------------------------------------------------
__global__ void cvt_k(const float* __restrict__ in, unsigned short* __restrict__ out, int n)
{
    int i = blockIdx.x * 256 + threadIdx.x;
    int stride = gridDim.x * 256;
    for (; i < n; i += stride) out[i] = f2bf(in[i]);
}

// ---------------------------------------------------------------------------
// GARCH: per-batch variance + 511-step scalar recurrence. 1 block, lane = batch.
// ---------------------------------------------------------------------------
__global__ __launch_bounds__(64) void garch_k(
    const float* __restrict__ xe, const float* __restrict__ omega,
    const float* __restrict__ alpha, const float* __restrict__ beta,
    float* __restrict__ vol)
{
    int b = threadIdx.x;
    float sm = 0.f, sq = 0.f;
    for (int t2 = 0; t2 < TT; t2++) {
        float r = xe[((long long)b * TT + t2) * EE + 5];
        sm += r; sq += r * r;
    }
    float mean = sm / 512.f;
    float var = (sq - 512.f * mean * mean) / 511.f;
    float h = var + 1e-6f;
    float om = log1pf(expf(omega[0]));
    float al = 0.2f / (1.f + expf(-alpha[0]));
    float be = 0.8f / (1.f + expf(-beta[0]));
    for (int t2 = 0; t2 < TT - 1; t2++) {
        float r = xe[((long long)b * TT + t2) * EE + 5];
        h = om + al * r * r + be * h;
    }
    vol[b] = sqrtf(h);
}

// ---------------------------------------------------------------------------
// Persistent LSTM v7 — halving butterfly + float2 LDS reads. (unchanged,
// 2.37 ms / 4.6 us/step measured; see round-6 notes.)
// ---------------------------------------------------------------------------
__global__ __launch_bounds__(512, 1) void lstm_wreg3_k(
    const float* __restrict__ xe, const float* __restrict__ w_hh,
    const float* __restrict__ w_ih, const float* __restrict__ b_ih,
    const float* __restrict__ b_hh,
    float* __restrict__ h0, float* __restrict__ h1,
    float* __restrict__ xT,
    unsigned* __restrict__ root)
{
    __shared__ float hs[8][544];      // h[b][k + 2*(k>>5)] (max 541)
    __shared__ float xs[8][8];        // x_t[b][e]
    __shared__ float wsx[16][4][6];   // w_ih slice for this dim group
    __shared__ float bsx[16][4];      // b_ih + b_hh

    int blk = blockIdx.x;             // 0..255
    int dgG = blk >> 3;               // 0..31 dim group
    int bG  = blk & 7;                // 0..7  batch group
    int tid = threadIdx.x;            // 0..511
    int i   = tid >> 5;               // 0..15 dim within group
    int ks  = tid & 31;               // 0..31 k-slice (16 k each)
    int D   = dgG * 16 + i;           // global dim 0..511
    int lane = tid & 63;
    int go  = lane & 32;              // 32-group base within wave

    // ---- permanent register-resident w_hh slice: w[gate][16] ----
    float w[4][16];
    #pragma unroll
    for (int g = 0; g < 4; g++) {
        const float* wr = w_hh + ((long long)(g * 512 + D)) * 512 + ks * 16;
        #pragma unroll
        for (int jj = 0; jj < 4; jj++) {
            float4 v4 = *(const float4*)(wr + jj * 4);
            w[g][jj * 4 + 0] = v4.x; w[g][jj * 4 + 1] = v4.y;
            w[g][jj * 4 + 2] = v4.z; w[g][jj * 4 + 3] = v4.w;
        }
    }
    // ---- x-projection weights/biases into LDS ----
    for (int idx = tid; idx < 16 * 4 * 6; idx += 512) {
        int i2 = idx / 24, g = (idx / 6) % 4, e = idx % 6;
        wsx[i2][g][e] = w_ih[((g * 512) + (dgG * 16 + i2)) * 6 + e];
    }
    if (tid < 64) {
        int i2 = tid >> 2, g = tid & 3;
        int D2 = dgG * 16 + i2;
        bsx[i2][g] = b_ih[g * 512 + D2] + b_hh[g * 512 + D2];
    }
    float c = 0.f;   // cell state for (D, b=ks) on lanes ks<8

    for (int t = 0; t < TT; t++) {
        const float* hin  = (t & 1) ? h1 : h0;
        float*       hout = (t & 1) ? h0 : h1;

        // ---- stage h[8][512] (16 KB) via one burst of coherent loads ----
        float hv[8];
        #pragma unroll
        for (int jj = 0; jj < 8; jj++) {
            int flat = jj * 512 + tid;            // 0..4095
            int row = flat >> 9, k = flat & 511;
            hv[jj] = __hip_atomic_load(&hin[(bG * 8 + row) * 512 + k],
                                       __ATOMIC_RELAXED,
                                       __HIP_MEMORY_SCOPE_AGENT);
        }
        if (tid < 64 && (tid & 7) < 6) {
            int b = tid >> 3, e = tid & 7;
            xs[b][e] = xe[((long long)(bG * 8 + b) * TT + t) * EE + e];
        }
        #pragma unroll
        for (int jj = 0; jj < 8; jj++) {
            int flat = jj * 512 + tid;
            int row = flat >> 9, k = flat & 511;
            hs[row][k + 2 * (k >> 5)] = hv[jj];
        }
        __syncthreads();

        // ---- outer-product dot: v[g*8+b] over this 16-k slice ----
        float v[32];
        #pragma unroll
        for (int s = 0; s < 32; s++) v[s] = 0.f;

        int kbase = ks * 16 + 2 * (ks >> 1);   // even -> 8B-aligned
        #pragma unroll
        for (int jj = 0; jj < 8; jj++) {
            float2 hb2[8];
            #pragma unroll
            for (int b = 0; b < 8; b++)
                hb2[b] = *(const float2*)&hs[b][kbase + jj * 2];
            #pragma unroll
            for (int g = 0; g < 4; g++)
                #pragma unroll
                for (int b = 0; b < 8; b++) {
                    v[g * 8 + b] += w[g][jj * 2]     * hb2[b].x;
                    v[g * 8 + b] += w[g][jj * 2 + 1] * hb2[b].y;
                }
        }

        // ---- halving butterfly over 32 lanes: lane ks ends with slot ks --
        float t16[16];
        #pragma unroll
        for (int j = 0; j < 16; j++) {
            float send = (ks & 16) ? v[j] : v[j + 16];
            float recv = __shfl_xor(send, 16);
            t16[j] = ((ks & 16) ? v[j + 16] : v[j]) + recv;
        }
        float t8[8];
        #pragma unroll
        for (int j = 0; j < 8; j++) {
            float send = (ks & 8) ? t16[j] : t16[j + 8];
            float recv = __shfl_xor(send, 8);
            t8[j] = ((ks & 8) ? t16[j + 8] : t16[j]) + recv;
        }
        float t4[4];
        #pragma unroll
        for (int j = 0; j < 4; j++) {
            float send = (ks & 4) ? t8[j] : t8[j + 4];
            float recv = __shfl_xor(send, 4);
            t4[j] = ((ks & 4) ? t8[j + 4] : t8[j]) + recv;
        }
        float t2[2];
        #pragma unroll
        for (int j = 0; j < 2; j++) {
            float send = (ks & 2) ? t4[j] : t4[j + 2];
            float recv = __shfl_xor(send, 2);
            t2[j] = ((ks & 2) ? t4[j + 2] : t4[j]) + recv;
        }
        float red;
        {
            float send = (ks & 1) ? t2[0] : t2[1];
            float recv = __shfl_xor(send, 1);
            red = ((ks & 1) ? t2[1] : t2[0]) + recv;
        }

        // ---- per-lane gate finalize: lane ks owns (g=ks>>3, b=ks&7) ----
        int gg_ = ks >> 3, bb_ = ks & 7;
        float x0 = xs[bb_][0], x1 = xs[bb_][1], x2 = xs[bb_][2];
        float x3 = xs[bb_][3], x4 = xs[bb_][4], x5 = xs[bb_][5];
        float p = red + x0 * wsx[i][gg_][0] + x1 * wsx[i][gg_][1]
                      + x2 * wsx[i][gg_][2] + x3 * wsx[i][gg_][3]
                      + x4 * wsx[i][gg_][4] + x5 * wsx[i][gg_][5]
                      + bsx[i][gg_];
        float sg = 1.f / (1.f + __expf(-p));
        float th = tanhf(p);
        float act = (gg_ == 2) ? th : sg;

        // gather i/f/g/o activations to lane b (all lanes execute shfl)
        float ai = __shfl(act, go + 0  + bb_);
        float af = __shfl(act, go + 8  + bb_);
        float ag = __shfl(act, go + 16 + bb_);
        float ao = __shfl(act, go + 24 + bb_);

        if (ks < 8) {
            int b = ks;
            c = af * c + ai * ag;
            float hn = ao * tanhf(c);
            __hip_atomic_store(&hout[(bG * 8 + b) * 512 + D], hn,
                               __ATOMIC_RELAXED, __HIP_MEMORY_SCOPE_AGENT);
            xT[((long long)t * 512 + D) * 64 + (bG * 8 + b)] = hn;
            // h stores must be at the coherence point before arrival.
            asm volatile("s_waitcnt vmcnt(0)" ::: "memory");
        }
        __syncthreads();   // all owners' stores landed; hs reads done

        if (t < TT - 1) {
            if (tid == 0) {
                __hip_atomic_fetch_add(&root[t * 8 + bG], 1u,
                    __ATOMIC_RELAXED, __HIP_MEMORY_SCOPE_AGENT);
                unsigned tries = 0;
                while (__hip_atomic_load(&root[t * 8 + bG], __ATOMIC_RELAXED,
                                         __HIP_MEMORY_SCOPE_AGENT) < 32u) {
                    __builtin_amdgcn_s_sleep(2);
                    if (++tries > 100000000u) break;   // fail loudly, never wedge
                }
            }
            __syncthreads();   // release whole block into step t+1
        }
    }
}

// ---------------------------------------------------------------------------
// Transpose xT[t][d][b] -> XB[b][t][d] bf16
// ---------------------------------------------------------------------------
__global__ __launch_bounds__(256) void transpose_k(
    const float* __restrict__ xT, unsigned short* __restrict__ XB_)
{
    __shared__ float tile[64][65];
    int dc = blockIdx.x, t = blockIdx.y;
    int tid = threadIdx.x;
    int bcol = tid & 63, grp = tid >> 6;
    #pragma unroll
    for (int j = 0; j < 16; j++) {
        int i = grp * 16 + j;
        tile[i][bcol] = xT[((long long)t * 512 + dc * 64 + i) * 64 + bcol];
    }
    __syncthreads();
    #pragma unroll
    for (int j = 0; j < 16; j++) {
        int brow = grp * 16 + j;
        float v = tile[bcol][brow];
        long long idx = ((long long)brow * TT + t) * DD + dc * 64 + bcol;
        XB_[idx] = f2bf(v);
    }
}

// ---------------------------------------------------------------------------
// Softmax over last dim (512), in-place on bf16 scores. One wave per row.
// ---------------------------------------------------------------------------
__global__ __launch_bounds__(256) void softmax_k(unsigned short* __restrict__ S)
{
    long long row = (long long)blockIdx.x * 4 + (threadIdx.x >> 6);
    int lane = threadIdx.x & 63;
    unsigned short* p = S + row * 512 + lane * 8;
    uint4 raw = *(const uint4*)p;
    unsigned short* u = (unsigned short*)&raw;
    float v[8];
    float m = -1e30f;
    #pragma unroll
    for (int j = 0; j < 8; j++) { v[j] = bf2f(u[j]); m = fmaxf(m, v[j]); }
    #pragma unroll
    for (int off = 1; off < 64; off <<= 1) m = fmaxf(m, __shfl_xor(m, off));
    float s = 0.f;
    #pragma unroll
    for (int j = 0; j < 8; j++) { v[j] = __expf(v[j] - m); s += v[j]; }
    #pragma unroll
    for (int off = 1; off < 64; off <<= 1) s += __shfl_xor(s, off);
    float inv = 1.f / s;
    unsigned int pk[4];
    #pragma unroll
    for (int j = 0; j < 4; j++)
        pk[j] = (unsigned int)f2bf(v[2 * j] * inv) | ((unsigned int)f2bf(v[2 * j + 1] * inv) << 16);
    *(uint4*)p = make_uint4(pk[0], pk[1], pk[2], pk[3]);
}

// ---------------------------------------------------------------------------
// Residual + LayerNorm: XB = LN(XB + Y)*g + b  (bf16 residual stream).
// ---------------------------------------------------------------------------
__global__ __launch_bounds__(256) void ln_k(
    unsigned short* XB_, const float* __restrict__ Y_,
    const float* __restrict__ g, const float* __restrict__ b2)
{
    long long row = (long long)blockIdx.x * 4 + (threadIdx.x >> 6);
    int lane = threadIdx.x & 63;
    long long base = row * 512 + lane * 8;
    float s[8];
    {
        uint4 xr = *(const uint4*)&XB_[base];
        const unsigned short* xu = (const unsigned short*)&xr;
        float4 y0 = *(const float4*)&Y_[base];
        float4 y1 = *(const float4*)&Y_[base + 4];
        s[0] = bf2f(xu[0]) + y0.x; s[1] = bf2f(xu[1]) + y0.y;
        s[2] = bf2f(xu[2]) + y0.z; s[3] = bf2f(xu[3]) + y0.w;
        s[4] = bf2f(xu[4]) + y1.x; s[5] = bf2f(xu[5]) + y1.y;
        s[6] = bf2f(xu[6]) + y1.z; s[7] = bf2f(xu[7]) + y1.w;
    }
    float sm = 0.f, sq = 0.f;
    #pragma unroll
    for (int j = 0; j < 8; j++) { sm += s[j]; sq += s[j] * s[j]; }
    #pragma unroll
    for (int off = 1; off < 64; off <<= 1) {
        sm += __shfl_xor(sm, off);
        sq += __shfl_xor(sq, off);
    }
    float mean = sm * (1.f / 512.f);
    float var = sq * (1.f / 512.f) - mean * mean;
    float rstd = rsqrtf(var + 1e-5f);
    int col = lane * 8;
    float o[8];
    #pragma unroll
    for (int j = 0; j < 8; j++) o[j] = (s[j] - mean) * rstd * g[col + j] + b2[col + j];
    unsigned int pk[4];
    #pragma unroll
    for (int j = 0; j < 4; j++)
        pk[j] = (unsigned int)f2bf(o[2 * j]) | ((unsigned int)f2bf(o[2 * j + 1]) << 16);
    *(uint4*)&XB_[base] = make_uint4(pk[0], pk[1], pk[2], pk[3]);
}

// ---------------------------------------------------------------------------
// Heads: garch_base + gate * ai_residual. One block per batch.
// ---------------------------------------------------------------------------
__global__ __launch_bounds__(128) void head_k(
    const unsigned short* __restrict__ XB_, const float* __restrict__ xe,
    const float* __restrict__ vol,
    const float* __restrict__ rh_w, const float* __restrict__ rh_b,
    const float* __restrict__ g1_w, const float* __restrict__ g1_b,
    const float* __restrict__ g2_w, const float* __restrict__ g2_b,
    const float* __restrict__ gp_w, const float* __restrict__ gp_b,
    float* __restrict__ out)
{
    int b = blockIdx.x, t = threadIdx.x;
    __shared__ float xl[512];
    __shared__ float hid[256];
    for (int j = t; j < 512; j += 128)
        xl[j] = bf2f(XB_[((long long)b * TT + (TT - 1)) * DD + j]);
    float gin[7];
    #pragma unroll
    for (int e = 0; e < 6; e++) gin[e] = xe[((long long)b * TT + (TT - 1)) * EE + e];
    gin[6] = vol[b];
    for (int j = t; j < 256; j += 128) {
        float s = g1_b[j];
        #pragma unroll
        for (int e = 0; e < 7; e++) s += g1_w[j * 7 + e] * gin[e];
        hid[j] = fmaxf(s, 0.f);
    }
    __syncthreads();
    for (int p = t; p < 96; p += 128) {
        float ai = rh_b[p];
        for (int j = 0; j < 512; j++) ai += xl[j] * rh_w[p * 512 + j];
        float gs = g2_b[p];
        for (int j = 0; j < 256; j++) gs += hid[j] * g2_w[p * 256 + j];
        float gate = 1.f / (1.f + expf(-gs));
        out[b * PP + p] = vol[b] * gp_w[p] + gp_b[p] + gate * ai;
    }
}

// ---------------------------------------------------------------------------
// Launch.  Workspace layout (bytes, total ~147.2 MB):
//   XB   bf16 residual  @ 0           (33554432)
//   Y    fp32 branch    @ 33554432    (67108864)   [aliases LSTM xT]
//   CH   chunk region   @ 100663296   (33554432)
//        QKVc @ +0 | SCc @ +12582912 | CTXc @ +29360128 ; HIDc @ +0 [FFN]
//   WB   bf16 weights   @ 134217728   (12582912)
//   HT0/HT1 h[b][d]     @ 146800640   (2 x 131072)
//   BAR  barrier slots  @ 147062784   (root 512x8 u32 = 16384)
//   VOL                 @ 147193856   (256)
// ---------------------------------------------------------------------------
extern "C" void kernel_launch(void* const* d_in, const int* in_sizes, int n_in,
                              void* d_out, int out_size, void* d_ws, size_t ws_size,
                              hipStream_t stream)
{
    const float* x_enc      = (const float*)d_in[0];
    const float* omega      = (const float*)d_in[4];
    const float* alpha      = (const float*)d_in[5];
    const float* beta       = (const float*)d_in[6];
    const float* gp_w       = (const float*)d_in[7];
    const float* gp_b       = (const float*)d_in[8];
    const float* w_ih       = (const float*)d_in[9];
    const float* w_hh       = (const float*)d_in[10];
    const float* b_ih       = (const float*)d_in[11];
    const float* b_hh       = (const float*)d_in[12];
    const float* attn_in_w  = (const float*)d_in[13];
    const float* attn_in_b  = (const float*)d_in[14];
    const float* attn_out_w = (const float*)d_in[15];
    const float* attn_out_b = (const float*)d_in[16];
    const float* ln1_g      = (const float*)d_in[17];
    const float* ln1_b      = (const float*)d_in[18];
    const float* ffn_w1     = (const float*)d_in[19];
    const float* ffn_b1     = (const float*)d_in[20];
    const float* ffn_w2     = (const float*)d_in[21];
    const float* ffn_b2     = (const float*)d_in[22];
    const float* ln2_g      = (const float*)d_in[23];
    const float* ln2_b      = (const float*)d_in[24];
    const float* rh_w       = (const float*)d_in[25];
    const float* rh_b       = (const float*)d_in[26];
    const float* g1_w       = (const float*)d_in[27];
    const float* g1_b       = (const float*)d_in[28];
    const float* g2_w       = (const float*)d_in[29];
    const float* g2_b       = (const float*)d_in[30];

    char* ws = (char*)d_ws;
    unsigned short* XB   = (unsigned short*)(ws + 0);
    float*          Y    = (float*)(ws + 33554432LL);
    float*          XT   = Y;
    unsigned short* QKVc = (unsigned short*)(ws + 100663296LL);
    unsigned short* SCc  = (unsigned short*)(ws + 113246208LL);
    unsigned short* CTXc = (unsigned short*)(ws + 130023424LL);
    unsigned short* HIDc = (unsigned short*)(ws + 100663296LL);
    unsigned short* WATI = (unsigned short*)(ws + 134217728LL);
    unsigned short* WATO = WATI + 1572864;
    unsigned short* WF1  = WATI + 2097152;
    unsigned short* WF2  = WATI + 4194304;
    float*          HT0  = (float*)(ws + 146800640LL);
    float*          HT1  = (float*)(ws + 146931712LL);
    unsigned*       ROOT = (unsigned*)(ws + 147062784LL);
    float*          VOL  = (float*)(ws + 147193856LL);

    hipMemsetAsync(HT0, 0, 131072, stream);
    hipMemsetAsync(ROOT, 0, 16384, stream);

    cvt_k<<<2048, 256, 0, stream>>>(attn_in_w,  WATI, 1572864);
    cvt_k<<<1024, 256, 0, stream>>>(attn_out_w, WATO, 524288);
    cvt_k<<<2048, 256, 0, stream>>>(ffn_w1,     WF1,  2097152);
    cvt_k<<<2048, 256, 0, stream>>>(ffn_w2,     WF2,  2097152);

    garch_k<<<1, 64, 0, stream>>>(x_enc, omega, alpha, beta, VOL);

    // Persistent LSTM v7: halving butterfly + float2 LDS reads.
    lstm_wreg3_k<<<256, 512, 0, stream>>>(x_enc, w_hh, w_ih, b_ih, b_hh,
                                          HT0, HT1, XT, ROOT);

    transpose_k<<<dim3(8, 512, 1), 256, 0, stream>>>(XT, XB);

    for (int l = 0; l < 2; l++) {
        // Attention, chunked over batches: 8 chunks x 8 batches (4096 rows)
        for (int c = 0; c < 8; c++) {
            long long rowOff = (long long)c * 8 * 512;
            gemm_bt<false, true, false, true><<<dim3(32, 12, 1), 256, 0, stream>>>(
                XB + rowOff * 512, 512, 0, 0,
                WATI + l * 786432, 512, 0, 0, attn_in_b + l * 1536,
                QKVc, 1536, 0, 0, 512, 1, 1.0f);
            gemm_bt<false, false, false, true><<<dim3(4, 4, 32), 256, 0, stream>>>(
                QKVc, 1536, 786432LL, 128LL, QKVc + 512, 1536, 786432LL, 128LL, nullptr,
                SCc, 512, 1048576LL, 262144LL, 128, 4, 0.088388347648318447f);
            softmax_k<<<4096, 256, 0, stream>>>(SCc);
            gemm_bt<true, false, false, true><<<dim3(4, 1, 32), 256, 0, stream>>>(
                SCc, 512, 1048576LL, 262144LL, QKVc + 1024, 1536, 786432LL, 128LL, nullptr,
                CTXc, 512, 262144LL, 128LL, 512, 4, 1.0f);
            gemm_bt<false, true, false, false><<<dim3(32, 4, 1), 256, 0, stream>>>(
                CTXc, 512, 0, 0, WATO + l * 262144, 512, 0, 0, attn_out_b + l * 512,
                Y + rowOff * 512, 512, 0, 0, 512, 1, 1.0f);
        }
        ln_k<<<8192, 256, 0, stream>>>(XB, Y, ln1_g + l * 512, ln1_b + l * 512);

        // FFN, chunked over rows: 4 chunks x 8192 rows
        for (int mc = 0; mc < 4; mc++) {
            long long rowOff = (long long)mc * 8192;
            gemm_bt<false, true, true, true><<<dim3(64, 16, 1), 256, 0, stream>>>(
                XB + rowOff * 512, 512, 0, 0,
                WF1 + l * 1048576, 512, 0, 0, ffn_b1 + l * 2048,
                HIDc, 2048, 0, 0, 512, 1, 1.0f);
            gemm_bt<false, true, false, false><<<dim3(64, 4, 1), 256, 0, stream>>>(
                HIDc, 2048, 0, 0, WF2 + l * 1048576, 2048, 0, 0, ffn_b2 + l * 512,
                Y + rowOff * 512, 512, 0, 0, 2048, 1, 1.0f);
        }
        ln_k<<<8192, 256, 0, stream>>>(XB, Y, ln2_g + l * 512, ln2_b + l * 512);
    }

    head_k<<<64, 128, 0, stream>>>(XB, x_enc, VOL, rh_w, rh_b,
                                   g1_w, g1_b, g2_w, g2_b, gp_w, gp_b,
                                   (float*)d_out);
}

// Round 9
// 3804.526 us; speedup vs baseline: 6.1963x; 1.1207x over previous
//
#include <hip/hip_runtime.h>
#include <hip/hip_bf16.h>

// Model dims
#define BB 64
#define TT 512
#define DD 512
#define EE 6
#define PP 96
#define NHH 4
#define HDD 128
#define FFF 2048

typedef short bf16x8 __attribute__((ext_vector_type(8)));
typedef float f32x4 __attribute__((ext_vector_type(4)));

__device__ __forceinline__ float bf2f(unsigned short u) {
    unsigned int x = ((unsigned int)u) << 16;
    return __uint_as_float(x);
}
__device__ __forceinline__ unsigned short f2bf(float f) {
    __hip_bfloat16 h = __float2bfloat16(f);
    return *reinterpret_cast<unsigned short*>(&h);
}

// Direct global->LDS 16B/lane async copy (gfx950). LDS base is WAVE-UNIFORM;
// HW adds lane*16. Global ptr is per-lane. (m97 pattern: +67% GEMM staging.)
__device__ __forceinline__ void gload_lds16(const unsigned short* g, unsigned short* l)
{
    __builtin_amdgcn_global_load_lds(
        (const __attribute__((address_space(1))) unsigned int*)g,
        (__attribute__((address_space(3))) unsigned int*)l, 16, 0, 0);
}

// ---------------------------------------------------------------------------
// Generic MFMA GEMM:  C[m][n] = alpha * sum_k A[m][k] * W[n][k]  (+bias[n])
// 128x128 tile, BK=32, 256 threads (4 waves, each a 64x64 quadrant of
// 4x4 mfma_f32_16x16x32_bf16). A (and W when !TRANSW) staged via
// global_load_lds width-16 into LINEAR [128][32] LDS tiles.
// TRANSW stages W[k*ldw+n] (V^T for P·V) via reg+scatter.
// Batched via blockIdx.z -> (b = z/Hdiv, h = z%Hdiv) offsets.
// ---------------------------------------------------------------------------
template<bool TRANSW, bool BIAS, bool RELU, bool OUTBF16>
__global__ __launch_bounds__(256) void gemm_bt(
    const unsigned short* __restrict__ A, int lda, long long aB, long long aH,
    const unsigned short* __restrict__ W, int ldw, long long wB, long long wH,
    const float* __restrict__ bias,
    void* __restrict__ Cv, int ldc, long long cB, long long cH,
    int K, int Hdiv, float alpha)
{
    __shared__ unsigned short As[128 * 32];
    __shared__ unsigned short Ws[128 * 32];
    int t = threadIdx.x;
    int z = blockIdx.z;
    int zb = z / Hdiv, zh = z - zb * Hdiv;
    long long aOff = (long long)zb * aB + (long long)zh * aH;
    long long wOff = (long long)zb * wB + (long long)zh * wH;
    long long cOff = (long long)zb * cB + (long long)zh * cH;
    int m0 = blockIdx.x * 128, n0 = blockIdx.y * 128;

    int wave = t >> 6, lane = t & 63;

    // global_load_lds staging: wave w covers rows [w*16,+16) and [64+w*16,+16);
    // lane l -> row +(l>>2), col (l&3)*8; LDS bytes l*16 = same cell (linear).
    int srow = wave * 16 + (lane >> 2);
    int scol = (lane & 3) * 8;
    const unsigned short* AgL = A + aOff + (long long)(m0 + srow) * lda + scol;
    const unsigned short* AgH = A + aOff + (long long)(m0 + 64 + srow) * lda + scol;
    unsigned short* AsL = &As[(wave * 16) * 32];
    unsigned short* AsH = &As[(64 + wave * 16) * 32];
    const unsigned short* WgL = W + wOff + (long long)(n0 + srow) * ldw + scol;
    const unsigned short* WgH = W + wOff + (long long)(n0 + 64 + srow) * ldw + scol;
    unsigned short* WsL = &Ws[(wave * 16) * 32];
    unsigned short* WsH = &Ws[(64 + wave * 16) * 32];

    // TRANSW scatter-staging geometry (PV only)
    int wk = t >> 3, wn = (t & 7) * 16;
    const unsigned short* WgT = W + wOff + n0 + wn;

    int wm = (wave & 1) * 64, wn2 = (wave >> 1) * 64;
    int lrow = lane & 15, quad = lane >> 4;

    f32x4 acc[4][4];
    #pragma unroll
    for (int i = 0; i < 4; i++)
        #pragma unroll
        for (int j = 0; j < 4; j++)
            acc[i][j] = (f32x4){0.f, 0.f, 0.f, 0.f};

    for (int k0 = 0; k0 < K; k0 += 32) {
        __syncthreads();   // prior compute done reading LDS
        gload_lds16(AgL + k0, AsL);
        gload_lds16(AgH + k0, AsH);
        if (!TRANSW) {
            gload_lds16(WgL + k0, WsL);
            gload_lds16(WgH + k0, WsH);
        } else {
            const unsigned short* p = WgT + (long long)(k0 + wk) * ldw;
            uint4 w0 = *(const uint4*)(p);
            uint4 w1 = *(const uint4*)(p + 8);
            const unsigned short* s0 = (const unsigned short*)&w0;
            const unsigned short* s1 = (const unsigned short*)&w1;
            #pragma unroll
            for (int j = 0; j < 8; j++) Ws[(wn + j) * 32 + wk] = s0[j];
            #pragma unroll
            for (int j = 0; j < 8; j++) Ws[(wn + 8 + j) * 32 + wk] = s1[j];
        }
        __syncthreads();   // drains vmcnt(0) -> LDS tiles ready
        bf16x8 af[4], bf[4];
        #pragma unroll
        for (int i = 0; i < 4; i++)
            af[i] = *(const bf16x8*)&As[(wm + i * 16 + lrow) * 32 + quad * 8];
        #pragma unroll
        for (int j = 0; j < 4; j++)
            bf[j] = *(const bf16x8*)&Ws[(wn2 + j * 16 + lrow) * 32 + quad * 8];
        #pragma unroll
        for (int i = 0; i < 4; i++)
            #pragma unroll
            for (int j = 0; j < 4; j++)
                acc[i][j] = __builtin_amdgcn_mfma_f32_16x16x32_bf16(af[i], bf[j], acc[i][j], 0, 0, 0);
    }

    #pragma unroll
    for (int i = 0; i < 4; i++) {
        #pragma unroll
        for (int j = 0; j < 4; j++) {
            #pragma unroll
            for (int r = 0; r < 4; r++) {
                int row = m0 + wm + i * 16 + quad * 4 + r;
                int col = n0 + wn2 + j * 16 + lrow;
                float v = acc[i][j][r] * alpha;
                if (BIAS) v += bias[col];
                if (RELU) v = fmaxf(v, 0.f);
                long long idx = cOff + (long long)row * ldc + col;
                if (OUTBF16) ((unsigned short*)Cv)[idx] = f2bf(v);
                else         ((float*)Cv)[idx] = v;
            }
        }
    }
}

// ---------------------------------------------------------------------------
__global__ void cvt_k(const float* __restrict__ in, unsigned short* __restrict__ out, int n)
{
    int i = blockIdx.x * 256 + threadIdx.x;
    int stride = gridDim.x * 256;
    for (; i < n; i += stride) out[i] = f2bf(in[i]);
}

// ---------------------------------------------------------------------------
// GARCH v2: parallel sums (8 threads/batch) + LDS-staged r^2 recurrence.
// One block, 512 threads. Replaces the single-wave serial version
// (~50us latency-bound -> ~8us).
// ---------------------------------------------------------------------------
__global__ __launch_bounds__(512) void garch2_k(
    const float* __restrict__ xe, const float* __restrict__ omega,
    const float* __restrict__ alpha, const float* __restrict__ beta,
    float* __restrict__ vol)
{
    __shared__ float r2s[64][513];   // padded: owners hit distinct banks
    int tid = threadIdx.x;
    int b = tid >> 3, j = tid & 7;
    float sm = 0.f, sq = 0.f;
    for (int t = j; t < TT; t += 8) {
        float r = xe[((long long)b * TT + t) * EE + 5];
        r2s[b][t] = r * r;
        sm += r; sq += r * r;
    }
    // reduce within each 8-lane group (groups never straddle waves)
    #pragma unroll
    for (int off = 1; off < 8; off <<= 1) {
        sm += __shfl_xor(sm, off);
        sq += __shfl_xor(sq, off);
    }
    __syncthreads();
    if (j == 0) {
        float mean = sm / 512.f;
        float var = (sq - 512.f * mean * mean) / 511.f;
        float h = var + 1e-6f;
        float om = log1pf(expf(omega[0]));
        float al = 0.2f / (1.f + expf(-alpha[0]));
        float be = 0.8f / (1.f + expf(-beta[0]));
        for (int t = 0; t < TT - 1; t++)
            h = om + al * r2s[b][t] + be * h;
        vol[b] = sqrtf(h);
    }
}

// ---------------------------------------------------------------------------
// Persistent LSTM v7 — halving butterfly + float2 LDS reads. (unchanged,
// 2.35 ms / 4.6 us/step measured.)
// ---------------------------------------------------------------------------
__global__ __launch_bounds__(512, 1) void lstm_wreg3_k(
    const float* __restrict__ xe, const float* __restrict__ w_hh,
    const float* __restrict__ w_ih, const float* __restrict__ b_ih,
    const float* __restrict__ b_hh,
    float* __restrict__ h0, float* __restrict__ h1,
    float* __restrict__ xT,
    unsigned* __restrict__ root)
{
    __shared__ float hs[8][544];      // h[b][k + 2*(k>>5)] (max 541)
    __shared__ float xs[8][8];        // x_t[b][e]
    __shared__ float wsx[16][4][6];   // w_ih slice for this dim group
    __shared__ float bsx[16][4];      // b_ih + b_hh

    int blk = blockIdx.x;             // 0..255
    int dgG = blk >> 3;               // 0..31 dim group
    int bG  = blk & 7;                // 0..7  batch group
    int tid = threadIdx.x;            // 0..511
    int i   = tid >> 5;               // 0..15 dim within group
    int ks  = tid & 31;               // 0..31 k-slice (16 k each)
    int D   = dgG * 16 + i;           // global dim 0..511
    int lane = tid & 63;
    int go  = lane & 32;              // 32-group base within wave

    // ---- permanent register-resident w_hh slice: w[gate][16] ----
    float w[4][16];
    #pragma unroll
    for (int g = 0; g < 4; g++) {
        const float* wr = w_hh + ((long long)(g * 512 + D)) * 512 + ks * 16;
        #pragma unroll
        for (int jj = 0; jj < 4; jj++) {
            float4 v4 = *(const float4*)(wr + jj * 4);
            w[g][jj * 4 + 0] = v4.x; w[g][jj * 4 + 1] = v4.y;
            w[g][jj * 4 + 2] = v4.z; w[g][jj * 4 + 3] = v4.w;
        }
    }
    // ---- x-projection weights/biases into LDS ----
    for (int idx = tid; idx < 16 * 4 * 6; idx += 512) {
        int i2 = idx / 24, g = (idx / 6) % 4, e = idx % 6;
        wsx[i2][g][e] = w_ih[((g * 512) + (dgG * 16 + i2)) * 6 + e];
    }
    if (tid < 64) {
        int i2 = tid >> 2, g = tid & 3;
        int D2 = dgG * 16 + i2;
        bsx[i2][g] = b_ih[g * 512 + D2] + b_hh[g * 512 + D2];
    }
    float c = 0.f;   // cell state for (D, b=ks) on lanes ks<8

    for (int t = 0; t < TT; t++) {
        const float* hin  = (t & 1) ? h1 : h0;
        float*       hout = (t & 1) ? h0 : h1;

        // ---- stage h[8][512] (16 KB) via one burst of coherent loads ----
        float hv[8];
        #pragma unroll
        for (int jj = 0; jj < 8; jj++) {
            int flat = jj * 512 + tid;            // 0..4095
            int row = flat >> 9, k = flat & 511;
            hv[jj] = __hip_atomic_load(&hin[(bG * 8 + row) * 512 + k],
                                       __ATOMIC_RELAXED,
                                       __HIP_MEMORY_SCOPE_AGENT);
        }
        if (tid < 64 && (tid & 7) < 6) {
            int b = tid >> 3, e = tid & 7;
            xs[b][e] = xe[((long long)(bG * 8 + b) * TT + t) * EE + e];
        }
        #pragma unroll
        for (int jj = 0; jj < 8; jj++) {
            int flat = jj * 512 + tid;
            int row = flat >> 9, k = flat & 511;
            hs[row][k + 2 * (k >> 5)] = hv[jj];
        }
        __syncthreads();

        // ---- outer-product dot: v[g*8+b] over this 16-k slice ----
        float v[32];
        #pragma unroll
        for (int s = 0; s < 32; s++) v[s] = 0.f;

        int kbase = ks * 16 + 2 * (ks >> 1);   // even -> 8B-aligned
        #pragma unroll
        for (int jj = 0; jj < 8; jj++) {
            float2 hb2[8];
            #pragma unroll
            for (int b = 0; b < 8; b++)
                hb2[b] = *(const float2*)&hs[b][kbase + jj * 2];
            #pragma unroll
            for (int g = 0; g < 4; g++)
                #pragma unroll
                for (int b = 0; b < 8; b++) {
                    v[g * 8 + b] += w[g][jj * 2]     * hb2[b].x;
                    v[g * 8 + b] += w[g][jj * 2 + 1] * hb2[b].y;
                }
        }

        // ---- halving butterfly over 32 lanes: lane ks ends with slot ks --
        float t16[16];
        #pragma unroll
        for (int j = 0; j < 16; j++) {
            float send = (ks & 16) ? v[j] : v[j + 16];
            float recv = __shfl_xor(send, 16);
            t16[j] = ((ks & 16) ? v[j + 16] : v[j]) + recv;
        }
        float t8[8];
        #pragma unroll
        for (int j = 0; j < 8; j++) {
            float send = (ks & 8) ? t16[j] : t16[j + 8];
            float recv = __shfl_xor(send, 8);
            t8[j] = ((ks & 8) ? t16[j + 8] : t16[j]) + recv;
        }
        float t4[4];
        #pragma unroll
        for (int j = 0; j < 4; j++) {
            float send = (ks & 4) ? t8[j] : t8[j + 4];
            float recv = __shfl_xor(send, 4);
            t4[j] = ((ks & 4) ? t8[j + 4] : t8[j]) + recv;
        }
        float t2[2];
        #pragma unroll
        for (int j = 0; j < 2; j++) {
            float send = (ks & 2) ? t4[j] : t4[j + 2];
            float recv = __shfl_xor(send, 2);
            t2[j] = ((ks & 2) ? t4[j + 2] : t4[j]) + recv;
        }
        float red;
        {
            float send = (ks & 1) ? t2[0] : t2[1];
            float recv = __shfl_xor(send, 1);
            red = ((ks & 1) ? t2[1] : t2[0]) + recv;
        }

        // ---- per-lane gate finalize: lane ks owns (g=ks>>3, b=ks&7) ----
        int gg_ = ks >> 3, bb_ = ks & 7;
        float x0 = xs[bb_][0], x1 = xs[bb_][1], x2 = xs[bb_][2];
        float x3 = xs[bb_][3], x4 = xs[bb_][4], x5 = xs[bb_][5];
        float p = red + x0 * wsx[i][gg_][0] + x1 * wsx[i][gg_][1]
                      + x2 * wsx[i][gg_][2] + x3 * wsx[i][gg_][3]
                      + x4 * wsx[i][gg_][4] + x5 * wsx[i][gg_][5]
                      + bsx[i][gg_];
        float sg = 1.f / (1.f + __expf(-p));
        float th = tanhf(p);
        float act = (gg_ == 2) ? th : sg;

        // gather i/f/g/o activations to lane b (all lanes execute shfl)
        float ai = __shfl(act, go + 0  + bb_);
        float af = __shfl(act, go + 8  + bb_);
        float ag = __shfl(act, go + 16 + bb_);
        float ao = __shfl(act, go + 24 + bb_);

        if (ks < 8) {
            int b = ks;
            c = af * c + ai * ag;
            float hn = ao * tanhf(c);
            __hip_atomic_store(&hout[(bG * 8 + b) * 512 + D], hn,
                               __ATOMIC_RELAXED, __HIP_MEMORY_SCOPE_AGENT);
            xT[((long long)t * 512 + D) * 64 + (bG * 8 + b)] = hn;
            // h stores must be at the coherence point before arrival.
            asm volatile("s_waitcnt vmcnt(0)" ::: "memory");
        }
        __syncthreads();   // all owners' stores landed; hs reads done

        if (t < TT - 1) {
            if (tid == 0) {
                __hip_atomic_fetch_add(&root[t * 8 + bG], 1u,
                    __ATOMIC_RELAXED, __HIP_MEMORY_SCOPE_AGENT);
                unsigned tries = 0;
                while (__hip_atomic_load(&root[t * 8 + bG], __ATOMIC_RELAXED,
                                         __HIP_MEMORY_SCOPE_AGENT) < 32u) {
                    __builtin_amdgcn_s_sleep(2);
                    if (++tries > 100000000u) break;   // fail loudly, never wedge
                }
            }
            __syncthreads();   // release whole block into step t+1
        }
    }
}

// ---------------------------------------------------------------------------
// Transpose xT[t][d][b] -> XB[b][t][d] bf16
// ---------------------------------------------------------------------------
__global__ __launch_bounds__(256) void transpose_k(
    const float* __restrict__ xT, unsigned short* __restrict__ XB_)
{
    __shared__ float tile[64][65];
    int dc = blockIdx.x, t = blockIdx.y;
    int tid = threadIdx.x;
    int bcol = tid & 63, grp = tid >> 6;
    #pragma unroll
    for (int j = 0; j < 16; j++) {
        int i = grp * 16 + j;
        tile[i][bcol] = xT[((long long)t * 512 + dc * 64 + i) * 64 + bcol];
    }
    __syncthreads();
    #pragma unroll
    for (int j = 0; j < 16; j++) {
        int brow = grp * 16 + j;
        float v = tile[bcol][brow];
        long long idx = ((long long)brow * TT + t) * DD + dc * 64 + bcol;
        XB_[idx] = f2bf(v);
    }
}

// ---------------------------------------------------------------------------
// Softmax over last dim (512), in-place on bf16 scores. One wave per row.
// ---------------------------------------------------------------------------
__global__ __launch_bounds__(256) void softmax_k(unsigned short* __restrict__ S)
{
    long long row = (long long)blockIdx.x * 4 + (threadIdx.x >> 6);
    int lane = threadIdx.x & 63;
    unsigned short* p = S + row * 512 + lane * 8;
    uint4 raw = *(const uint4*)p;
    unsigned short* u = (unsigned short*)&raw;
    float v[8];
    float m = -1e30f;
    #pragma unroll
    for (int j = 0; j < 8; j++) { v[j] = bf2f(u[j]); m = fmaxf(m, v[j]); }
    #pragma unroll
    for (int off = 1; off < 64; off <<= 1) m = fmaxf(m, __shfl_xor(m, off));
    float s = 0.f;
    #pragma unroll
    for (int j = 0; j < 8; j++) { v[j] = __expf(v[j] - m); s += v[j]; }
    #pragma unroll
    for (int off = 1; off < 64; off <<= 1) s += __shfl_xor(s, off);
    float inv = 1.f / s;
    unsigned int pk[4];
    #pragma unroll
    for (int j = 0; j < 4; j++)
        pk[j] = (unsigned int)f2bf(v[2 * j] * inv) | ((unsigned int)f2bf(v[2 * j + 1] * inv) << 16);
    *(uint4*)p = make_uint4(pk[0], pk[1], pk[2], pk[3]);
}

// ---------------------------------------------------------------------------
// Residual + LayerNorm: XB = LN(XB + Y)*g + b.  Y is now bf16 (32 MB).
// ---------------------------------------------------------------------------
__global__ __launch_bounds__(256) void ln_k(
    unsigned short* XB_, const unsigned short* __restrict__ Y_,
    const float* __restrict__ g, const float* __restrict__ b2)
{
    long long row = (long long)blockIdx.x * 4 + (threadIdx.x >> 6);
    int lane = threadIdx.x & 63;
    long long base = row * 512 + lane * 8;
    float s[8];
    {
        uint4 xr = *(const uint4*)&XB_[base];
        uint4 yr = *(const uint4*)&Y_[base];
        const unsigned short* xu = (const unsigned short*)&xr;
        const unsigned short* yu = (const unsigned short*)&yr;
        #pragma unroll
        for (int j = 0; j < 8; j++) s[j] = bf2f(xu[j]) + bf2f(yu[j]);
    }
    float sm = 0.f, sq = 0.f;
    #pragma unroll
    for (int j = 0; j < 8; j++) { sm += s[j]; sq += s[j] * s[j]; }
    #pragma unroll
    for (int off = 1; off < 64; off <<= 1) {
        sm += __shfl_xor(sm, off);
        sq += __shfl_xor(sq, off);
    }
    float mean = sm * (1.f / 512.f);
    float var = sq * (1.f / 512.f) - mean * mean;
    float rstd = rsqrtf(var + 1e-5f);
    int col = lane * 8;
    float o[8];
    #pragma unroll
    for (int j = 0; j < 8; j++) o[j] = (s[j] - mean) * rstd * g[col + j] + b2[col + j];
    unsigned int pk[4];
    #pragma unroll
    for (int j = 0; j < 4; j++)
        pk[j] = (unsigned int)f2bf(o[2 * j]) | ((unsigned int)f2bf(o[2 * j + 1]) << 16);
    *(uint4*)&XB_[base] = make_uint4(pk[0], pk[1], pk[2], pk[3]);
}

// ---------------------------------------------------------------------------
// Heads: garch_base + gate * ai_residual. One block per batch.
// ---------------------------------------------------------------------------
__global__ __launch_bounds__(128) void head_k(
    const unsigned short* __restrict__ XB_, const float* __restrict__ xe,
    const float* __restrict__ vol,
    const float* __restrict__ rh_w, const float* __restrict__ rh_b,
    const float* __restrict__ g1_w, const float* __restrict__ g1_b,
    const float* __restrict__ g2_w, const float* __restrict__ g2_b,
    const float* __restrict__ gp_w, const float* __restrict__ gp_b,
    float* __restrict__ out)
{
    int b = blockIdx.x, t = threadIdx.x;
    __shared__ float xl[512];
    __shared__ float hid[256];
    for (int j = t; j < 512; j += 128)
        xl[j] = bf2f(XB_[((long long)b * TT + (TT - 1)) * DD + j]);
    float gin[7];
    #pragma unroll
    for (int e = 0; e < 6; e++) gin[e] = xe[((long long)b * TT + (TT - 1)) * EE + e];
    gin[6] = vol[b];
    for (int j = t; j < 256; j += 128) {
        float s = g1_b[j];
        #pragma unroll
        for (int e = 0; e < 7; e++) s += g1_w[j * 7 + e] * gin[e];
        hid[j] = fmaxf(s, 0.f);
    }
    __syncthreads();
    for (int p = t; p < 96; p += 128) {
        float ai = rh_b[p];
        for (int j = 0; j < 512; j++) ai += xl[j] * rh_w[p * 512 + j];
        float gs = g2_b[p];
        for (int j = 0; j < 256; j++) gs += hid[j] * g2_w[p * 256 + j];
        float gate = 1.f / (1.f + expf(-gs));
        out[b * PP + p] = vol[b] * gp_w[p] + gp_b[p] + gate * ai;
    }
}

// ---------------------------------------------------------------------------
// Launch.  Workspace layout (bytes, total ~147.2 MB):
//   XB   bf16 residual      @ 0           (33554432)
//   YB   bf16 branch        @ 33554432    (33554432)
//   CH   chunk region 64MB  @ 67108864    [aliases LSTM xT fp32 64MB]
//        QKVc @ +0 (25165824) | SCc @ +25165824 (33554432)
//        CTX written into QKVc's dead Q slot (ldc=1536) during PV.
//        HIDc @ +0 (33554432) during FFN.
//   WB   bf16 weights       @ 134217728   (12582912)
//   HT0/HT1 h[b][d]         @ 146800640   (2 x 131072)
//   BAR  barrier slots      @ 147062784   (root 512x8 u32 = 16384)
//   VOL                     @ 147193856   (256)
// Attention chunking: 4 chunks x 16 batches (halves dispatch count, doubles
// per-dispatch grids: QK^T 1024 blk, PV 256 blk, proj 256 blk).
// ---------------------------------------------------------------------------
extern "C" void kernel_launch(void* const* d_in, const int* in_sizes, int n_in,
                              void* d_out, int out_size, void* d_ws, size_t ws_size,
                              hipStream_t stream)
{
    const float* x_enc      = (const float*)d_in[0];
    const float* omega      = (const float*)d_in[4];
    const float* alpha      = (const float*)d_in[5];
    const float* beta       = (const float*)d_in[6];
    const float* gp_w       = (const float*)d_in[7];
    const float* gp_b       = (const float*)d_in[8];
    const float* w_ih       = (const float*)d_in[9];
    const float* w_hh       = (const float*)d_in[10];
    const float* b_ih       = (const float*)d_in[11];
    const float* b_hh       = (const float*)d_in[12];
    const float* attn_in_w  = (const float*)d_in[13];
    const float* attn_in_b  = (const float*)d_in[14];
    const float* attn_out_w = (const float*)d_in[15];
    const float* attn_out_b = (const float*)d_in[16];
    const float* ln1_g      = (const float*)d_in[17];
    const float* ln1_b      = (const float*)d_in[18];
    const float* ffn_w1     = (const float*)d_in[19];
    const float* ffn_b1     = (const float*)d_in[20];
    const float* ffn_w2     = (const float*)d_in[21];
    const float* ffn_b2     = (const float*)d_in[22];
    const float* ln2_g      = (const float*)d_in[23];
    const float* ln2_b      = (const float*)d_in[24];
    const float* rh_w       = (const float*)d_in[25];
    const float* rh_b       = (const float*)d_in[26];
    const float* g1_w       = (const float*)d_in[27];
    const float* g1_b       = (const float*)d_in[28];
    const float* g2_w       = (const float*)d_in[29];
    const float* g2_b       = (const float*)d_in[30];

    char* ws = (char*)d_ws;
    unsigned short* XB   = (unsigned short*)(ws + 0);
    unsigned short* YB   = (unsigned short*)(ws + 33554432LL);
    float*          XT   = (float*)(ws + 67108864LL);
    unsigned short* QKVc = (unsigned short*)(ws + 67108864LL);
    unsigned short* SCc  = (unsigned short*)(ws + 67108864LL + 25165824LL);
    unsigned short* WATI = (unsigned short*)(ws + 134217728LL);
    unsigned short* WATO = WATI + 1572864;
    unsigned short* WF1  = WATI + 2097152;
    unsigned short* WF2  = WATI + 4194304;
    unsigned short* HIDc = QKVc;
    float*          HT0  = (float*)(ws + 146800640LL);
    float*          HT1  = (float*)(ws + 146931712LL);
    unsigned*       ROOT = (unsigned*)(ws + 147062784LL);
    float*          VOL  = (float*)(ws + 147193856LL);

    hipMemsetAsync(HT0, 0, 131072, stream);
    hipMemsetAsync(ROOT, 0, 16384, stream);

    cvt_k<<<2048, 256, 0, stream>>>(attn_in_w,  WATI, 1572864);
    cvt_k<<<1024, 256, 0, stream>>>(attn_out_w, WATO, 524288);
    cvt_k<<<2048, 256, 0, stream>>>(ffn_w1,     WF1,  2097152);
    cvt_k<<<2048, 256, 0, stream>>>(ffn_w2,     WF2,  2097152);

    garch2_k<<<1, 512, 0, stream>>>(x_enc, omega, alpha, beta, VOL);

    // Persistent LSTM v7: halving butterfly + float2 LDS reads.
    lstm_wreg3_k<<<256, 512, 0, stream>>>(x_enc, w_hh, w_ih, b_ih, b_hh,
                                          HT0, HT1, XT, ROOT);

    transpose_k<<<dim3(8, 512, 1), 256, 0, stream>>>(XT, XB);

    for (int l = 0; l < 2; l++) {
        // Attention, 4 chunks x 16 batches (8192 rows each)
        for (int c = 0; c < 4; c++) {
            long long rowOff = (long long)c * 16 * 512;
            // QKV projection: [8192 x 512] @ [1536 x 512]^T -> QKVc [8192 x 1536]
            gemm_bt<false, true, false, true><<<dim3(64, 12, 1), 256, 0, stream>>>(
                XB + rowOff * 512, 512, 0, 0,
                WATI + l * 786432, 512, 0, 0, attn_in_b + l * 1536,
                QKVc, 1536, 0, 0, 512, 1, 1.0f);
            // Scores: per (b,h): Q [512x128] @ K^T -> SCc [512x512]
            gemm_bt<false, false, false, true><<<dim3(4, 4, 64), 256, 0, stream>>>(
                QKVc, 1536, 786432LL, 128LL, QKVc + 512, 1536, 786432LL, 128LL, nullptr,
                SCc, 512, 1048576LL, 262144LL, 128, 4, 0.088388347648318447f);
            softmax_k<<<8192, 256, 0, stream>>>(SCc);
            // PV: P [512x512] @ V (TRANSW) -> CTX written into dead Q slot
            gemm_bt<true, false, false, true><<<dim3(4, 1, 64), 256, 0, stream>>>(
                SCc, 512, 1048576LL, 262144LL, QKVc + 1024, 1536, 786432LL, 128LL, nullptr,
                QKVc, 1536, 786432LL, 128LL, 512, 4, 1.0f);
            // Out-projection: CTX [8192 x 512] (q-slot, lda=1536) -> YB bf16
            gemm_bt<false, true, false, true><<<dim3(64, 4, 1), 256, 0, stream>>>(
                QKVc, 1536, 0, 0, WATO + l * 262144, 512, 0, 0, attn_out_b + l * 512,
                YB + rowOff * 512, 512, 0, 0, 512, 1, 1.0f);
        }
        ln_k<<<8192, 256, 0, stream>>>(XB, YB, ln1_g + l * 512, ln1_b + l * 512);

        // FFN, chunked over rows: 4 chunks x 8192 rows
        for (int mc = 0; mc < 4; mc++) {
            long long rowOff = (long long)mc * 8192;
            gemm_bt<false, true, true, true><<<dim3(64, 16, 1), 256, 0, stream>>>(
                XB + rowOff * 512, 512, 0, 0,
                WF1 + l * 1048576, 512, 0, 0, ffn_b1 + l * 2048,
                HIDc, 2048, 0, 0, 512, 1, 1.0f);
            gemm_bt<false, true, false, true><<<dim3(64, 4, 1), 256, 0, stream>>>(
                HIDc, 2048, 0, 0, WF2 + l * 1048576, 2048, 0, 0, ffn_b2 + l * 512,
                YB + rowOff * 512, 512, 0, 0, 2048, 1, 1.0f);
        }
        ln_k<<<8192, 256, 0, stream>>>(XB, YB, ln2_g + l * 512, ln2_b + l * 512);
    }

    head_k<<<64, 128, 0, stream>>>(XB, x_enc, VOL, rh_w, rh_b,
                                   g1_w, g1_b, g2_w, g2_b, gp_w, gp_b,
                                   (float*)d_out);
}